// Round 2
// baseline (2355.420 us; speedup 1.0000x reference)
//
#include <hip/hip_runtime.h>

typedef __attribute__((ext_vector_type(8))) short short8;
typedef __attribute__((ext_vector_type(4))) float f32x4;
typedef unsigned short u16;
typedef unsigned int u32;

#define DEV static __device__ __forceinline__

// B=4, C=128, P=128, D=128, H=8, R=16, G=512
constexpr long long NEL = 4LL * 128 * 128 * 128; // 8388608 elements per [B,C,P,D] tensor

DEV float us2f(u16 u) { union { u32 i; float f; } x; x.i = (u32)u << 16; return x.f; }
DEV u16 f2us(float f) {
  union { float f; u32 i; } x; x.f = f;
  u32 r = x.i + 0x7fffu + ((x.i >> 16) & 1u);
  return (u16)(r >> 16);
}
DEV u32 pack2(float a, float b) { return (u32)f2us(a) | ((u32)f2us(b) << 16); }
DEV float gelu_f(float x) { return 0.5f * x * (1.0f + erff(x * 0.70710678118654752f)); }

// ---------------- LayerNorm (f32 -> f32), 1 row per wave ----------------
__global__ __launch_bounds__(256) void ln_kernel(const float* __restrict__ xin,
                                                 const float* __restrict__ gw,
                                                 const float* __restrict__ bw,
                                                 float* __restrict__ out) {
  int wv = threadIdx.x >> 6, lane = threadIdx.x & 63;
  long long row = (long long)blockIdx.x * 4 + wv;
  const float* xr = xin + row * 128;
  float a0 = xr[lane], a1 = xr[lane + 64];
  float s = a0 + a1, q = a0 * a0 + a1 * a1;
  #pragma unroll
  for (int off = 32; off >= 1; off >>= 1) { s += __shfl_xor(s, off); q += __shfl_xor(q, off); }
  float m = s * (1.f / 128.f);
  float v = q * (1.f / 128.f) - m * m;
  float r = rsqrtf(v + 1e-5f);
  float* orow = out + row * 128;
  orow[lane]      = (a0 - m) * r * gw[lane]      + bw[lane];
  orow[lane + 64] = (a1 - m) * r * gw[lane + 64] + bw[lane + 64];
}

// ---------------- GEMM: out[row, o] = sum_d A[row,d] * W[(b),o,d], 64 rows/block ----------------
// EPI: 0 plain f32, 1 transposed(c<->p) f32, 2 bias+gelu f32, 3 bias+resid f32
template <int EPI>
__global__ __launch_bounds__(256) void gemm128(const float* __restrict__ A, const float* __restrict__ W,
                                               int wbatched, const float* __restrict__ bias,
                                               const float* __restrict__ resid,
                                               float* __restrict__ outf) {
  __shared__ u16 AL[64][136];
  __shared__ u16 WL[128][136];
  int rowbase = blockIdx.x * 64;
  int bb = rowbase >> 14;
  const float* Wb = W + (wbatched ? (long long)bb * 16384 : 0);
  int tid = threadIdx.x, l = tid & 63, w = tid >> 6;
  for (int idx = tid; idx < 64 * 64; idx += 256) {
    int r = idx >> 6, d2 = idx & 63;
    const float2 v = *(const float2*)(A + (long long)(rowbase + r) * 128 + d2 * 2);
    *(u32*)&AL[r][d2 * 2] = pack2(v.x, v.y);
  }
  for (int idx = tid; idx < 128 * 64; idx += 256) {
    int o = idx >> 6, d2 = idx & 63;
    const float2 v = *(const float2*)(Wb + (long long)o * 128 + d2 * 2);
    *(u32*)&WL[o][d2 * 2] = pack2(v.x, v.y);
  }
  __syncthreads();
  f32x4 acc[8];
  #pragma unroll
  for (int cf = 0; cf < 8; ++cf) acc[cf] = (f32x4){0.f, 0.f, 0.f, 0.f};
  int arow = w * 16 + (l & 15);
  int kg = (l >> 4) * 8;
  #pragma unroll
  for (int k = 0; k < 4; ++k) {
    short8 a = *(const short8*)&AL[arow][k * 32 + kg];
    #pragma unroll
    for (int cf = 0; cf < 8; ++cf) {
      short8 b = *(const short8*)&WL[cf * 16 + (l & 15)][k * 32 + kg];
      acc[cf] = __builtin_amdgcn_mfma_f32_16x16x32_bf16(a, b, acc[cf], 0, 0, 0);
    }
  }
  #pragma unroll
  for (int cf = 0; cf < 8; ++cf) {
    int col = cf * 16 + (l & 15);
    float bv = 0.f;
    if (EPI >= 2) bv = bias[col];
    #pragma unroll
    for (int j = 0; j < 4; ++j) {
      int row = rowbase + w * 16 + (l >> 4) * 4 + j;
      float v = acc[cf][j];
      if (EPI == 0) {
        outf[(long long)row * 128 + col] = v;
      } else if (EPI == 1) {
        int b2i = row >> 14, c = (row >> 7) & 127, p = row & 127;
        outf[((long long)(b2i * 128 + p) * 128 + c) * 128 + col] = v;
      } else if (EPI == 2) {
        outf[(long long)row * 128 + col] = gelu_f(v + bv);
      } else {
        long long o = (long long)row * 128 + col;
        outf[o] = v + bv + resid[o];
      }
    }
  }
}

// ---------------- time attention: per (b,c) block ----------------
__global__ __launch_bounds__(256) void time_attn(const float* __restrict__ qzn,
                                                 const float* __restrict__ tu,
                                                 const float* __restrict__ tv,
                                                 float* __restrict__ accg) {
  __shared__ u16 ZL[128][128];   // qzn slice, bf16
  __shared__ float S[64][128];   // half of the score matrix
  int bc = blockIdx.x;
  const float* zb = qzn + (long long)bc * 16384;
  const float* ub = tu + (long long)bc * 16384;
  const float* vb = tv + (long long)bc * 16384;
  int tid = threadIdx.x, lane = tid & 63, wv = tid >> 6;
  int half = tid >> 7, dcol = tid & 127;
  int ty = tid >> 4, tx = tid & 15;
  for (int idx = tid; idx < 128 * 64; idx += 256) {
    int qq = idx >> 6, d2 = idx & 63;
    const float2 v = *(const float2*)(zb + qq * 128 + d2 * 2);
    *(u32*)&ZL[qq][d2 * 2] = pack2(v.x, v.y);
  }
  float accv[64];
  #pragma unroll
  for (int i = 0; i < 64; ++i) accv[i] = 0.f;
  for (int h = 0; h < 8; ++h) {
    int ko = h * 16;
    #pragma unroll
    for (int ph = 0; ph < 2; ++ph) {
      float sc[4][8];
      #pragma unroll
      for (int i = 0; i < 4; ++i)
        #pragma unroll
        for (int j = 0; j < 8; ++j) sc[i][j] = 0.f;
      #pragma unroll
      for (int rc = 0; rc < 4; ++rc) {
        float4 uu[4], vv[8];
        #pragma unroll
        for (int i = 0; i < 4; ++i)
          uu[i] = *(const float4*)(ub + (ph * 64 + ty * 4 + i) * 128 + ko + rc * 4);
        #pragma unroll
        for (int j = 0; j < 8; ++j)
          vv[j] = *(const float4*)(vb + (tx * 8 + j) * 128 + ko + rc * 4);
        #pragma unroll
        for (int i = 0; i < 4; ++i)
          #pragma unroll
          for (int j = 0; j < 8; ++j)
            sc[i][j] += uu[i].x * vv[j].x + uu[i].y * vv[j].y + uu[i].z * vv[j].z + uu[i].w * vv[j].w;
      }
      __syncthreads();  // previous PV done reading S (and ZL staged, first iter)
      #pragma unroll
      for (int i = 0; i < 4; ++i)
        #pragma unroll
        for (int j = 0; j < 8; ++j) S[ty * 4 + i][tx * 8 + j] = sc[i][j] * 0.25f;
      __syncthreads();
      // softmax: 4 waves x 16 rows
      for (int rr = 0; rr < 16; ++rr) {
        int row = wv * 16 + rr;
        float a = S[row][lane], b = S[row][lane + 64];
        float mx = fmaxf(a, b);
        #pragma unroll
        for (int off = 32; off >= 1; off >>= 1) mx = fmaxf(mx, __shfl_xor(mx, off));
        float ea = __expf(a - mx), eb = __expf(b - mx);
        float sm = ea + eb;
        #pragma unroll
        for (int off = 32; off >= 1; off >>= 1) sm += __shfl_xor(sm, off);
        float inv = 1.f / sm;
        S[row][lane] = ea * inv;
        S[row][lane + 64] = eb * inv;
      }
      __syncthreads();
      // PV: acc[p][d] += sum_q S[p][q] * qzn[q][d]
      for (int q0 = 0; q0 < 128; q0 += 16) {
        float z[16];
        #pragma unroll
        for (int j = 0; j < 16; ++j) z[j] = us2f(ZL[q0 + j][dcol]);
        #pragma unroll
        for (int i = 0; i < 32; ++i) {
          const float4* sp = (const float4*)&S[2 * i + half][q0];
          float4 s0 = sp[0], s1 = sp[1], s2 = sp[2], s3 = sp[3];
          accv[ph * 32 + i] +=
              s0.x * z[0] + s0.y * z[1] + s0.z * z[2] + s0.w * z[3] +
              s1.x * z[4] + s1.y * z[5] + s1.z * z[6] + s1.w * z[7] +
              s2.x * z[8] + s2.y * z[9] + s2.z * z[10] + s2.w * z[11] +
              s3.x * z[12] + s3.y * z[13] + s3.z * z[14] + s3.w * z[15];
        }
      }
    }
  }
  float* og = accg + (long long)bc * 16384;
  #pragma unroll
  for (int i = 0; i < 64; ++i) {
    int p = (i >> 5) * 64 + (i & 31) * 2 + half;
    og[p * 128 + dcol] = accv[i] * 0.125f;  // mean over H=8; first writer of acc
  }
}

// ---------------- channel attention: per (b,p) block ----------------
__global__ __launch_bounds__(256) void chan_attn(const float* __restrict__ qzn,
                                                 const float* __restrict__ cuT,
                                                 const float* __restrict__ cvT,
                                                 float* __restrict__ accg) {
  __shared__ float S[128][128];
  int bp = blockIdx.x;
  int b = bp >> 7, p = bp & 127;
  const float* ub = cuT + (long long)bp * 16384;
  const float* vb = cvT + (long long)bp * 16384;
  int tid = threadIdx.x, lane = tid & 63, wv = tid >> 6;
  int half = tid >> 7, dcol = tid & 127;
  int ty = tid >> 4, tx = tid & 15;
  float macc[64];
  #pragma unroll
  for (int i = 0; i < 64; ++i) macc[i] = 0.f;
  for (int h = 0; h < 8; ++h) {
    int ko = h * 16;
    __syncthreads();  // previous macc accumulation done reading S
    #pragma unroll
    for (int ps = 0; ps < 2; ++ps) {
      float sc[4][8];
      #pragma unroll
      for (int i = 0; i < 4; ++i)
        #pragma unroll
        for (int j = 0; j < 8; ++j) sc[i][j] = 0.f;
      #pragma unroll
      for (int rc = 0; rc < 4; ++rc) {
        float4 uu[4], vv[8];
        #pragma unroll
        for (int i = 0; i < 4; ++i)
          uu[i] = *(const float4*)(ub + (ps * 64 + ty * 4 + i) * 128 + ko + rc * 4);
        #pragma unroll
        for (int j = 0; j < 8; ++j)
          vv[j] = *(const float4*)(vb + (tx * 8 + j) * 128 + ko + rc * 4);
        #pragma unroll
        for (int i = 0; i < 4; ++i)
          #pragma unroll
          for (int j = 0; j < 8; ++j)
            sc[i][j] += uu[i].x * vv[j].x + uu[i].y * vv[j].y + uu[i].z * vv[j].z + uu[i].w * vv[j].w;
      }
      #pragma unroll
      for (int i = 0; i < 4; ++i)
        #pragma unroll
        for (int j = 0; j < 8; ++j) S[ps * 64 + ty * 4 + i][tx * 8 + j] = sc[i][j] * 0.25f;
    }
    __syncthreads();
    for (int rr = 0; rr < 32; ++rr) {
      int row = wv * 32 + rr;
      float a = S[row][lane], b = S[row][lane + 64];
      float mx = fmaxf(a, b);
      #pragma unroll
      for (int off = 32; off >= 1; off >>= 1) mx = fmaxf(mx, __shfl_xor(mx, off));
      float ea = __expf(a - mx), eb = __expf(b - mx);
      float sm = ea + eb;
      #pragma unroll
      for (int off = 32; off >= 1; off >>= 1) sm += __shfl_xor(sm, off);
      float inv = 1.f / sm;
      S[row][lane] = ea * inv;
      S[row][lane + 64] = eb * inv;
    }
    __syncthreads();
    #pragma unroll
    for (int i = 0; i < 64; ++i) macc[i] += S[2 * i + half][dcol];
  }
  const float* zb = qzn + (long long)b * 128 * 16384;
  float* ob = accg + (long long)b * 128 * 16384;
  #pragma unroll
  for (int i = 0; i < 64; ++i) {
    int c = 2 * i + half;
    long long o = ((long long)c * 128 + p) * 128 + dcol;
    ob[o] += macc[i] * 0.125f * zb[o];
  }
}

// ---------------- topic transpose: topicT[b][d][g] = bf16(topic[b][g][d]) ----------------
__global__ __launch_bounds__(256) void topic_transpose(const float* __restrict__ topic, u16* __restrict__ topicT) {
  __shared__ u16 tile[64][136];
  int b = blockIdx.x >> 3, gc = blockIdx.x & 7;
  const float* tb = topic + (long long)b * 65536;
  for (int idx = threadIdx.x; idx < 64 * 64; idx += 256) {
    int g = idx >> 6, d2 = idx & 63;
    const float2 v = *(const float2*)(tb + (long long)(gc * 64 + g) * 128 + d2 * 2);
    *(u32*)&tile[g][d2 * 2] = pack2(v.x, v.y);
  }
  __syncthreads();
  u16* to = topicT + (long long)b * 65536;
  for (int idx = threadIdx.x; idx < 128 * 64; idx += 256) {
    int d = idx >> 6, g = idx & 63;
    to[d * 512 + gc * 64 + g] = tile[g][d];
  }
}

// ---------------- topic branch: 32 rows/block, MFMA both phases ----------------
__global__ __launch_bounds__(256) void topic_kernel(const float* __restrict__ qzn,
                                                    const float* __restrict__ topic,
                                                    const u16* __restrict__ topicT,
                                                    float* __restrict__ accg) {
  __shared__ u16 AL[32][136];
  __shared__ u16 QG[32][520];
  __shared__ u16 Tb[9216];   // phase A: [64][136] from topic; phase B: [128][72] from topicT
  __shared__ float inv_s[32];
  int rowbase = blockIdx.x * 32;
  int b = rowbase >> 14;
  const float* tb = topic + (long long)b * 65536;
  const u32* tbtu = (const u32*)(topicT + (long long)b * 65536);
  int tid = threadIdx.x, l = tid & 63, w = tid >> 6;
  int rsel = w & 1, csel = w >> 1;
  for (int idx = tid; idx < 32 * 64; idx += 256) {
    int r = idx >> 6, d2 = idx & 63;
    const float2 v = *(const float2*)(qzn + (long long)(rowbase + r) * 128 + d2 * 2);
    *(u32*)&AL[r][d2 * 2] = pack2(v.x, v.y);
  }
  int arow = rsel * 16 + (l & 15);
  int kg = (l >> 4) * 8;
  // Phase A: qg = relu(qzn @ topic^T), chunks of 64 g
  for (int gc = 0; gc < 8; ++gc) {
    __syncthreads();
    for (int idx = tid; idx < 64 * 64; idx += 256) {
      int g = idx >> 6, d2 = idx & 63;
      const float2 v = *(const float2*)(tb + (long long)(gc * 64 + g) * 128 + d2 * 2);
      *(u32*)&Tb[g * 136 + d2 * 2] = pack2(v.x, v.y);
    }
    __syncthreads();
    f32x4 pa[2];
    pa[0] = (f32x4){0.f, 0.f, 0.f, 0.f};
    pa[1] = pa[0];
    #pragma unroll
    for (int k = 0; k < 4; ++k) {
      short8 a = *(const short8*)&AL[arow][k * 32 + kg];
      #pragma unroll
      for (int cf = 0; cf < 2; ++cf) {
        short8 bb = *(const short8*)&Tb[(csel * 32 + cf * 16 + (l & 15)) * 136 + k * 32 + kg];
        pa[cf] = __builtin_amdgcn_mfma_f32_16x16x32_bf16(a, bb, pa[cf], 0, 0, 0);
      }
    }
    #pragma unroll
    for (int cf = 0; cf < 2; ++cf)
      #pragma unroll
      for (int j = 0; j < 4; ++j) {
        int rl = rsel * 16 + (l >> 4) * 4 + j;
        int gcol = gc * 64 + csel * 32 + cf * 16 + (l & 15);
        QG[rl][gcol] = f2us(fmaxf(pa[cf][j], 0.f));
      }
  }
  __syncthreads();
  {
    int row = tid >> 3, s = tid & 7;
    float sum = 0.f;
    for (int i = 0; i < 64; ++i) sum += us2f(QG[row][s * 64 + i]);
    sum += __shfl_xor(sum, 1);
    sum += __shfl_xor(sum, 2);
    sum += __shfl_xor(sum, 4);
    if (s == 0) inv_s[row] = 1.f / fmaxf(sum, 1e-6f);
  }
  // Phase B: m_g = (qg * inv) @ topic, K = 512 in chunks of 64
  f32x4 ba[4];
  #pragma unroll
  for (int cf = 0; cf < 4; ++cf) ba[cf] = (f32x4){0.f, 0.f, 0.f, 0.f};
  for (int gc = 0; gc < 8; ++gc) {
    __syncthreads();
    for (int idx = tid; idx < 128 * 32; idx += 256) {
      int d = idx >> 5, g2 = idx & 31;
      *(u32*)&Tb[d * 72 + g2 * 2] = tbtu[d * 256 + gc * 32 + g2];
    }
    __syncthreads();
    #pragma unroll
    for (int k = 0; k < 2; ++k) {
      short8 a = *(const short8*)&QG[arow][gc * 64 + k * 32 + kg];
      #pragma unroll
      for (int cf = 0; cf < 4; ++cf) {
        short8 bb = *(const short8*)&Tb[(csel * 64 + cf * 16 + (l & 15)) * 72 + k * 32 + kg];
        ba[cf] = __builtin_amdgcn_mfma_f32_16x16x32_bf16(a, bb, ba[cf], 0, 0, 0);
      }
    }
  }
  #pragma unroll
  for (int cf = 0; cf < 4; ++cf)
    #pragma unroll
    for (int j = 0; j < 4; ++j) {
      int rl = rsel * 16 + (l >> 4) * 4 + j;
      int col = csel * 64 + cf * 16 + (l & 15);
      long long o = (long long)(rowbase + rl) * 128 + col;
      accg[o] += ba[cf][j] * inv_s[rl];
    }
}

// ---------------- combine (in place): acc = 0.5*(unary + qz + acc) ----------------
__global__ __launch_bounds__(256) void combine_kernel(const float* __restrict__ qz, const float* __restrict__ un,
                                                      float* __restrict__ acc) {
  long long i = ((long long)blockIdx.x * 256 + threadIdx.x) * 4;
  float4 q = *(const float4*)(qz + i);
  float4 u = *(const float4*)(un + i);
  float4 a = *(const float4*)(acc + i);
  float4 r;
  r.x = 0.5f * (q.x + u.x + a.x);
  r.y = 0.5f * (q.y + u.y + a.y);
  r.z = 0.5f * (q.z + u.z + a.z);
  r.w = 0.5f * (q.w + u.w + a.w);
  *(float4*)(acc + i) = r;
}

extern "C" void kernel_launch(void* const* d_in, const int* in_sizes, int n_in,
                              void* d_out, int out_size, void* d_ws, size_t ws_size,
                              hipStream_t stream) {
  const float* qz    = (const float*)d_in[0];
  const float* unary = (const float*)d_in[1];
  const float* tuw   = (const float*)d_in[2];
  const float* tvw   = (const float*)d_in[3];
  const float* cuw   = (const float*)d_in[4];
  const float* cvw   = (const float*)d_in[5];
  const float* topic = (const float*)d_in[6];
  const float* gam   = (const float*)d_in[7];
  const float* bet   = (const float*)d_in[8];
  const float* w1    = (const float*)d_in[9];
  const float* b1    = (const float*)d_in[10];
  const float* w2    = (const float*)d_in[11];
  const float* b2    = (const float*)d_in[12];
  float* out = (float*)d_out;

  float* ws   = (float*)d_ws;
  float* qzn  = ws;                 // [B,C,P,D] f32
  float* bufU = ws + NEL;           // tu / cuT / xln
  float* bufV = ws + 2 * NEL;       // tv / cvT / hmid
  float* accb = ws + 3 * NEL;       // m_t + m_c + m_g, then x (in place)
  u16* topicT = (u16*)(ws + 4 * NEL);

  // 1. qzn = LN(qz)
  ln_kernel<<<16384, 256, 0, stream>>>(qz, gam, bet, qzn);
  // 2-3. tu, tv
  gemm128<0><<<1024, 256, 0, stream>>>(qzn, tuw, 1, nullptr, nullptr, bufU);
  gemm128<0><<<1024, 256, 0, stream>>>(qzn, tvw, 1, nullptr, nullptr, bufV);
  // 4. time attention -> accb (=)
  time_attn<<<512, 256, 0, stream>>>(qzn, bufU, bufV, accb);
  // 5-6. cu, cv (transposed layout [b,p,c,o])
  gemm128<1><<<1024, 256, 0, stream>>>(qzn, cuw, 1, nullptr, nullptr, bufU);
  gemm128<1><<<1024, 256, 0, stream>>>(qzn, cvw, 1, nullptr, nullptr, bufV);
  // 7. channel attention -> accb (+=)
  chan_attn<<<512, 256, 0, stream>>>(qzn, bufU, bufV, accb);
  // 8-9. topic branch -> accb (+=)
  topic_transpose<<<32, 256, 0, stream>>>(topic, topicT);
  topic_kernel<<<2048, 256, 0, stream>>>(qzn, topic, topicT, accb);
  // 10. x = 0.5*(unary + qz + accb)  (in place in accb)
  combine_kernel<<<8192, 256, 0, stream>>>(qz, unary, accb);
  // 11. xln = LN(x)
  ln_kernel<<<16384, 256, 0, stream>>>(accb, gam, bet, bufU);
  // 12. hmid = gelu(xln @ w1^T + b1)
  gemm128<2><<<1024, 256, 0, stream>>>(bufU, w1, 0, b1, nullptr, bufV);
  // 13. out = x + hmid @ w2^T + b2  (f32)
  gemm128<3><<<1024, 256, 0, stream>>>(bufV, w2, 0, b2, accb, out);
}

// Round 3
// 519.631 us; speedup vs baseline: 4.5329x; 4.5329x over previous
//
#include <hip/hip_runtime.h>

typedef __attribute__((ext_vector_type(8))) short short8;
typedef __attribute__((ext_vector_type(4))) float f32x4;
typedef unsigned short u16;
typedef unsigned int u32;

#define DEV static __device__ __forceinline__

// B=4, C=128, P=128, D=128, H=8, R=16, G=512
constexpr long long NEL = 4LL * 128 * 128 * 128; // 8388608 elements per [B,C,P,D] tensor

DEV float us2f(u16 u) { union { u32 i; float f; } x; x.i = (u32)u << 16; return x.f; }
DEV u16 f2us(float f) {
  union { float f; u32 i; } x; x.f = f;
  u32 r = x.i + 0x7fffu + ((x.i >> 16) & 1u);
  return (u16)(r >> 16);
}
DEV u32 pack2(float a, float b) { return (u32)f2us(a) | ((u32)f2us(b) << 16); }
DEV float gelu_f(float x) { return 0.5f * x * (1.0f + erff(x * 0.70710678118654752f)); }

// ---------------- LayerNorm (f32 -> f32), 1 row per wave ----------------
__global__ __launch_bounds__(256) void ln_kernel(const float* __restrict__ xin,
                                                 const float* __restrict__ gw,
                                                 const float* __restrict__ bw,
                                                 float* __restrict__ out) {
  int wv = threadIdx.x >> 6, lane = threadIdx.x & 63;
  long long row = (long long)blockIdx.x * 4 + wv;
  const float* xr = xin + row * 128;
  float a0 = xr[lane], a1 = xr[lane + 64];
  float s = a0 + a1, q = a0 * a0 + a1 * a1;
  #pragma unroll
  for (int off = 32; off >= 1; off >>= 1) { s += __shfl_xor(s, off); q += __shfl_xor(q, off); }
  float m = s * (1.f / 128.f);
  float v = q * (1.f / 128.f) - m * m;
  float r = rsqrtf(v + 1e-5f);
  float* orow = out + row * 128;
  orow[lane]      = (a0 - m) * r * gw[lane]      + bw[lane];
  orow[lane + 64] = (a1 - m) * r * gw[lane + 64] + bw[lane + 64];
}

// ---------------- GEMM: out[row, o] = sum_d A[row,d] * W[(b),o,d], 64 rows/block ----------------
// EPI: 2 bias+gelu f32, 3 bias+resid f32, 4 plain bf16, 5 transposed(c<->p) bf16
template <int EPI>
__global__ __launch_bounds__(256) void gemm128(const float* __restrict__ A, const float* __restrict__ W,
                                               int wbatched, const float* __restrict__ bias,
                                               const float* __restrict__ resid,
                                               float* __restrict__ outf, u16* __restrict__ outb) {
  __shared__ u16 AL[64][136];
  __shared__ u16 WL[128][136];
  int rowbase = blockIdx.x * 64;
  int bb = rowbase >> 14;
  const float* Wb = W + (wbatched ? (long long)bb * 16384 : 0);
  int tid = threadIdx.x, l = tid & 63, w = tid >> 6;
  for (int idx = tid; idx < 64 * 64; idx += 256) {
    int r = idx >> 6, d2 = idx & 63;
    const float2 v = *(const float2*)(A + (long long)(rowbase + r) * 128 + d2 * 2);
    *(u32*)&AL[r][d2 * 2] = pack2(v.x, v.y);
  }
  for (int idx = tid; idx < 128 * 64; idx += 256) {
    int o = idx >> 6, d2 = idx & 63;
    const float2 v = *(const float2*)(Wb + (long long)o * 128 + d2 * 2);
    *(u32*)&WL[o][d2 * 2] = pack2(v.x, v.y);
  }
  __syncthreads();
  f32x4 acc[8];
  #pragma unroll
  for (int cf = 0; cf < 8; ++cf) acc[cf] = (f32x4){0.f, 0.f, 0.f, 0.f};
  int arow = w * 16 + (l & 15);
  int kg = (l >> 4) * 8;
  #pragma unroll
  for (int k = 0; k < 4; ++k) {
    short8 a = *(const short8*)&AL[arow][k * 32 + kg];
    #pragma unroll
    for (int cf = 0; cf < 8; ++cf) {
      short8 b = *(const short8*)&WL[cf * 16 + (l & 15)][k * 32 + kg];
      acc[cf] = __builtin_amdgcn_mfma_f32_16x16x32_bf16(a, b, acc[cf], 0, 0, 0);
    }
  }
  #pragma unroll
  for (int cf = 0; cf < 8; ++cf) {
    int col = cf * 16 + (l & 15);
    float bv = 0.f;
    if (EPI == 2 || EPI == 3) bv = bias[col];
    #pragma unroll
    for (int j = 0; j < 4; ++j) {
      int row = rowbase + w * 16 + (l >> 4) * 4 + j;
      float v = acc[cf][j];
      if (EPI == 2) {
        outf[(long long)row * 128 + col] = gelu_f(v + bv);
      } else if (EPI == 3) {
        long long o = (long long)row * 128 + col;
        outf[o] = v + bv + resid[o];
      } else if (EPI == 4) {
        outb[(long long)row * 128 + col] = f2us(v);
      } else {
        int b2i = row >> 14, c = (row >> 7) & 127, p = row & 127;
        outb[((long long)(b2i * 128 + p) * 128 + c) * 128 + col] = f2us(v);
      }
    }
  }
}

// ---------------- time attention (MFMA, sum-of-softmax over heads, single PV) ----------------
// block = (b,c); 4 waves, each owns 32 p-rows.
__global__ __launch_bounds__(256) void time_attn(const u16* __restrict__ tu,
                                                 const u16* __restrict__ tv,
                                                 const float* __restrict__ qzn,
                                                 float* __restrict__ accg) {
  __shared__ u16 ZT[128][136];      // qzn transposed: ZT[d][q]
  __shared__ u16 SP[4][32][136];    // per-wave summed softmax (bf16)
  int bc = blockIdx.x;
  const u16* ub = tu + (long long)bc * 16384;
  const u16* vb = tv + (long long)bc * 16384;
  const float* zb = qzn + (long long)bc * 16384;
  int tid = threadIdx.x, l = tid & 63, w = tid >> 6;
  int lo = l & 15, hi = l >> 4;
  int p0 = w * 32;
  // stage ZT (coalesced global read, scalar transposed LDS write)
  for (int idx = tid; idx < 8192; idx += 256) {
    int dp = idx & 63, q = idx >> 6;
    float2 v = *(const float2*)(zb + q * 128 + dp * 2);
    ZT[2 * dp][q] = f2us(v.x);
    ZT[2 * dp + 1][q] = f2us(v.y);
  }
  const short8 z8 = {0, 0, 0, 0, 0, 0, 0, 0};
  const f32x4 z4 = {0.f, 0.f, 0.f, 0.f};
  f32x4 ssum[2][8];
  #pragma unroll
  for (int i = 0; i < 2; ++i)
    #pragma unroll
    for (int cf = 0; cf < 8; ++cf) ssum[i][cf] = z4;
  bool act = hi < 2;
  for (int h = 0; h < 8; ++h) {
    int koff = h * 16 + hi * 8;  // valid only when hi<2 (k 16..31 zero-padded)
    short8 a[2];
    #pragma unroll
    for (int i = 0; i < 2; ++i)
      a[i] = act ? *(const short8*)(ub + (p0 + i * 16 + lo) * 128 + koff) : z8;
    f32x4 s[2][8];
    #pragma unroll
    for (int cf = 0; cf < 8; ++cf) {
      short8 bf = act ? *(const short8*)(vb + (cf * 16 + lo) * 128 + koff) : z8;
      #pragma unroll
      for (int i = 0; i < 2; ++i)
        s[i][cf] = __builtin_amdgcn_mfma_f32_16x16x32_bf16(a[i], bf, z4, 0, 0, 0);
    }
    // row max over 8 col-tiles + 16 lanes (groups of 16: xor 1,2,4,8)
    float mx[2][4], rs[2][4];
    #pragma unroll
    for (int i = 0; i < 2; ++i)
      #pragma unroll
      for (int j = 0; j < 4; ++j) {
        float m = s[i][0][j];
        #pragma unroll
        for (int cf = 1; cf < 8; ++cf) m = fmaxf(m, s[i][cf][j]);
        #pragma unroll
        for (int off = 1; off <= 8; off <<= 1) m = fmaxf(m, __shfl_xor(m, off));
        mx[i][j] = m;
      }
    #pragma unroll
    for (int i = 0; i < 2; ++i)
      #pragma unroll
      for (int cf = 0; cf < 8; ++cf)
        #pragma unroll
        for (int j = 0; j < 4; ++j)
          s[i][cf][j] = __expf((s[i][cf][j] - mx[i][j]) * 0.25f);
    #pragma unroll
    for (int i = 0; i < 2; ++i)
      #pragma unroll
      for (int j = 0; j < 4; ++j) {
        float t = s[i][0][j];
        #pragma unroll
        for (int cf = 1; cf < 8; ++cf) t += s[i][cf][j];
        #pragma unroll
        for (int off = 1; off <= 8; off <<= 1) t += __shfl_xor(t, off);
        rs[i][j] = 1.f / t;
      }
    #pragma unroll
    for (int i = 0; i < 2; ++i)
      #pragma unroll
      for (int cf = 0; cf < 8; ++cf)
        #pragma unroll
        for (int j = 0; j < 4; ++j)
          ssum[i][cf][j] += s[i][cf][j] * rs[i][j];
  }
  // spill summed softmax to LDS (bf16) in row-major for A-fragment reads
  #pragma unroll
  for (int i = 0; i < 2; ++i)
    #pragma unroll
    for (int cf = 0; cf < 8; ++cf)
      #pragma unroll
      for (int j = 0; j < 4; ++j)
        SP[w][i * 16 + hi * 4 + j][cf * 16 + lo] = f2us(ssum[i][cf][j]);
  __syncthreads();
  // PV: out[32 x 128] = SP[w] @ ZT^T, K=128
  f32x4 acc[2][8];
  #pragma unroll
  for (int i = 0; i < 2; ++i)
    #pragma unroll
    for (int dt = 0; dt < 8; ++dt) acc[i][dt] = z4;
  #pragma unroll
  for (int kk = 0; kk < 4; ++kk) {
    short8 a[2];
    #pragma unroll
    for (int i = 0; i < 2; ++i)
      a[i] = *(const short8*)&SP[w][i * 16 + lo][kk * 32 + hi * 8];
    #pragma unroll
    for (int dt = 0; dt < 8; ++dt) {
      short8 bf = *(const short8*)&ZT[dt * 16 + lo][kk * 32 + hi * 8];
      #pragma unroll
      for (int i = 0; i < 2; ++i)
        acc[i][dt] = __builtin_amdgcn_mfma_f32_16x16x32_bf16(a[i], bf, acc[i][dt], 0, 0, 0);
    }
  }
  float* og = accg + (long long)bc * 16384;
  #pragma unroll
  for (int i = 0; i < 2; ++i)
    #pragma unroll
    for (int dt = 0; dt < 8; ++dt)
      #pragma unroll
      for (int j = 0; j < 4; ++j)
        og[(p0 + i * 16 + hi * 4 + j) * 128 + dt * 16 + lo] = acc[i][dt][j] * 0.125f;
}

// ---------------- channel attention (MFMA QK, sum-of-softmax, elementwise epilogue) ----------------
// block = (b,p); 4 waves, each owns 32 c-rows. No LDS.
__global__ __launch_bounds__(256) void chan_attn(const u16* __restrict__ cuT,
                                                 const u16* __restrict__ cvT,
                                                 const float* __restrict__ qzn,
                                                 float* __restrict__ accg) {
  int bp = blockIdx.x;
  int b = bp >> 7, p = bp & 127;
  const u16* ub = cuT + (long long)bp * 16384;
  const u16* vb = cvT + (long long)bp * 16384;
  int tid = threadIdx.x, l = tid & 63, w = tid >> 6;
  int lo = l & 15, hi = l >> 4;
  int c0 = w * 32;
  const short8 z8 = {0, 0, 0, 0, 0, 0, 0, 0};
  const f32x4 z4 = {0.f, 0.f, 0.f, 0.f};
  f32x4 ssum[2][8];
  #pragma unroll
  for (int i = 0; i < 2; ++i)
    #pragma unroll
    for (int cf = 0; cf < 8; ++cf) ssum[i][cf] = z4;
  bool act = hi < 2;
  for (int h = 0; h < 8; ++h) {
    int koff = h * 16 + hi * 8;
    short8 a[2];
    #pragma unroll
    for (int i = 0; i < 2; ++i)
      a[i] = act ? *(const short8*)(ub + (c0 + i * 16 + lo) * 128 + koff) : z8;
    f32x4 s[2][8];
    #pragma unroll
    for (int cf = 0; cf < 8; ++cf) {
      short8 bf = act ? *(const short8*)(vb + (cf * 16 + lo) * 128 + koff) : z8;
      #pragma unroll
      for (int i = 0; i < 2; ++i)
        s[i][cf] = __builtin_amdgcn_mfma_f32_16x16x32_bf16(a[i], bf, z4, 0, 0, 0);
    }
    float mx[2][4], rs[2][4];
    #pragma unroll
    for (int i = 0; i < 2; ++i)
      #pragma unroll
      for (int j = 0; j < 4; ++j) {
        float m = s[i][0][j];
        #pragma unroll
        for (int cf = 1; cf < 8; ++cf) m = fmaxf(m, s[i][cf][j]);
        #pragma unroll
        for (int off = 1; off <= 8; off <<= 1) m = fmaxf(m, __shfl_xor(m, off));
        mx[i][j] = m;
      }
    #pragma unroll
    for (int i = 0; i < 2; ++i)
      #pragma unroll
      for (int cf = 0; cf < 8; ++cf)
        #pragma unroll
        for (int j = 0; j < 4; ++j)
          s[i][cf][j] = __expf((s[i][cf][j] - mx[i][j]) * 0.25f);
    #pragma unroll
    for (int i = 0; i < 2; ++i)
      #pragma unroll
      for (int j = 0; j < 4; ++j) {
        float t = s[i][0][j];
        #pragma unroll
        for (int cf = 1; cf < 8; ++cf) t += s[i][cf][j];
        #pragma unroll
        for (int off = 1; off <= 8; off <<= 1) t += __shfl_xor(t, off);
        rs[i][j] = 1.f / t;
      }
    #pragma unroll
    for (int i = 0; i < 2; ++i)
      #pragma unroll
      for (int cf = 0; cf < 8; ++cf)
        #pragma unroll
        for (int j = 0; j < 4; ++j)
          ssum[i][cf][j] += s[i][cf][j] * rs[i][j];
  }
  // m_c[c,p,o] += mean_h(attn)[c,o] * qzn[b,c,p,o]
  const float* zb = qzn + (long long)b * 2097152;
  float* ob = accg + (long long)b * 2097152;
  #pragma unroll
  for (int i = 0; i < 2; ++i)
    #pragma unroll
    for (int cf = 0; cf < 8; ++cf)
      #pragma unroll
      for (int j = 0; j < 4; ++j) {
        int c = c0 + i * 16 + hi * 4 + j;
        int o = cf * 16 + lo;
        long long off = ((long long)c * 128 + p) * 128 + o;
        ob[off] += ssum[i][cf][j] * 0.125f * zb[off];
      }
}

// ---------------- topic transpose: topicT[b][d][g] = bf16(topic[b][g][d]) ----------------
__global__ __launch_bounds__(256) void topic_transpose(const float* __restrict__ topic, u16* __restrict__ topicT) {
  __shared__ u16 tile[64][136];
  int b = blockIdx.x >> 3, gc = blockIdx.x & 7;
  const float* tb = topic + (long long)b * 65536;
  for (int idx = threadIdx.x; idx < 64 * 64; idx += 256) {
    int g = idx >> 6, d2 = idx & 63;
    const float2 v = *(const float2*)(tb + (long long)(gc * 64 + g) * 128 + d2 * 2);
    *(u32*)&tile[g][d2 * 2] = pack2(v.x, v.y);
  }
  __syncthreads();
  u16* to = topicT + (long long)b * 65536;
  for (int idx = threadIdx.x; idx < 128 * 64; idx += 256) {
    int d = idx >> 6, g = idx & 63;
    to[d * 512 + gc * 64 + g] = tile[g][d];
  }
}

// ---------------- topic branch: 32 rows/block, MFMA both phases ----------------
__global__ __launch_bounds__(256) void topic_kernel(const float* __restrict__ qzn,
                                                    const float* __restrict__ topic,
                                                    const u16* __restrict__ topicT,
                                                    float* __restrict__ accg) {
  __shared__ u16 AL[32][136];
  __shared__ u16 QG[32][520];
  __shared__ u16 Tb[9216];   // phase A: [64][136] from topic; phase B: [128][72] from topicT
  __shared__ float inv_s[32];
  int rowbase = blockIdx.x * 32;
  int b = rowbase >> 14;
  const float* tb = topic + (long long)b * 65536;
  const u32* tbtu = (const u32*)(topicT + (long long)b * 65536);
  int tid = threadIdx.x, l = tid & 63, w = tid >> 6;
  int rsel = w & 1, csel = w >> 1;
  for (int idx = tid; idx < 32 * 64; idx += 256) {
    int r = idx >> 6, d2 = idx & 63;
    const float2 v = *(const float2*)(qzn + (long long)(rowbase + r) * 128 + d2 * 2);
    *(u32*)&AL[r][d2 * 2] = pack2(v.x, v.y);
  }
  int arow = rsel * 16 + (l & 15);
  int kg = (l >> 4) * 8;
  // Phase A: qg = relu(qzn @ topic^T), chunks of 64 g
  for (int gc = 0; gc < 8; ++gc) {
    __syncthreads();
    for (int idx = tid; idx < 64 * 64; idx += 256) {
      int g = idx >> 6, d2 = idx & 63;
      const float2 v = *(const float2*)(tb + (long long)(gc * 64 + g) * 128 + d2 * 2);
      *(u32*)&Tb[g * 136 + d2 * 2] = pack2(v.x, v.y);
    }
    __syncthreads();
    f32x4 pa[2];
    pa[0] = (f32x4){0.f, 0.f, 0.f, 0.f};
    pa[1] = pa[0];
    #pragma unroll
    for (int k = 0; k < 4; ++k) {
      short8 a = *(const short8*)&AL[arow][k * 32 + kg];
      #pragma unroll
      for (int cf = 0; cf < 2; ++cf) {
        short8 bb = *(const short8*)&Tb[(csel * 32 + cf * 16 + (l & 15)) * 136 + k * 32 + kg];
        pa[cf] = __builtin_amdgcn_mfma_f32_16x16x32_bf16(a, bb, pa[cf], 0, 0, 0);
      }
    }
    #pragma unroll
    for (int cf = 0; cf < 2; ++cf)
      #pragma unroll
      for (int j = 0; j < 4; ++j) {
        int rl = rsel * 16 + (l >> 4) * 4 + j;
        int gcol = gc * 64 + csel * 32 + cf * 16 + (l & 15);
        QG[rl][gcol] = f2us(fmaxf(pa[cf][j], 0.f));
      }
  }
  __syncthreads();
  {
    int row = tid >> 3, s = tid & 7;
    float sum = 0.f;
    for (int i = 0; i < 64; ++i) sum += us2f(QG[row][s * 64 + i]);
    sum += __shfl_xor(sum, 1);
    sum += __shfl_xor(sum, 2);
    sum += __shfl_xor(sum, 4);
    if (s == 0) inv_s[row] = 1.f / fmaxf(sum, 1e-6f);
  }
  // Phase B: m_g = (qg * inv) @ topic, K = 512 in chunks of 64
  f32x4 ba[4];
  #pragma unroll
  for (int cf = 0; cf < 4; ++cf) ba[cf] = (f32x4){0.f, 0.f, 0.f, 0.f};
  for (int gc = 0; gc < 8; ++gc) {
    __syncthreads();
    for (int idx = tid; idx < 128 * 32; idx += 256) {
      int d = idx >> 5, g2 = idx & 31;
      *(u32*)&Tb[d * 72 + g2 * 2] = tbtu[d * 256 + gc * 32 + g2];
    }
    __syncthreads();
    #pragma unroll
    for (int k = 0; k < 2; ++k) {
      short8 a = *(const short8*)&QG[arow][gc * 64 + k * 32 + kg];
      #pragma unroll
      for (int cf = 0; cf < 4; ++cf) {
        short8 bb = *(const short8*)&Tb[(csel * 64 + cf * 16 + (l & 15)) * 72 + k * 32 + kg];
        ba[cf] = __builtin_amdgcn_mfma_f32_16x16x32_bf16(a, bb, ba[cf], 0, 0, 0);
      }
    }
  }
  #pragma unroll
  for (int cf = 0; cf < 4; ++cf)
    #pragma unroll
    for (int j = 0; j < 4; ++j) {
      int rl = rsel * 16 + (l >> 4) * 4 + j;
      int col = csel * 64 + cf * 16 + (l & 15);
      long long o = (long long)(rowbase + rl) * 128 + col;
      accg[o] += ba[cf][j] * inv_s[rl];
    }
}

// ---------------- combine (in place): acc = 0.5*(unary + qz + acc) ----------------
__global__ __launch_bounds__(256) void combine_kernel(const float* __restrict__ qz, const float* __restrict__ un,
                                                      float* __restrict__ acc) {
  long long i = ((long long)blockIdx.x * 256 + threadIdx.x) * 4;
  float4 q = *(const float4*)(qz + i);
  float4 u = *(const float4*)(un + i);
  float4 a = *(const float4*)(acc + i);
  float4 r;
  r.x = 0.5f * (q.x + u.x + a.x);
  r.y = 0.5f * (q.y + u.y + a.y);
  r.z = 0.5f * (q.z + u.z + a.z);
  r.w = 0.5f * (q.w + u.w + a.w);
  *(float4*)(acc + i) = r;
}

extern "C" void kernel_launch(void* const* d_in, const int* in_sizes, int n_in,
                              void* d_out, int out_size, void* d_ws, size_t ws_size,
                              hipStream_t stream) {
  const float* qz    = (const float*)d_in[0];
  const float* unary = (const float*)d_in[1];
  const float* tuw   = (const float*)d_in[2];
  const float* tvw   = (const float*)d_in[3];
  const float* cuw   = (const float*)d_in[4];
  const float* cvw   = (const float*)d_in[5];
  const float* topic = (const float*)d_in[6];
  const float* gam   = (const float*)d_in[7];
  const float* bet   = (const float*)d_in[8];
  const float* w1    = (const float*)d_in[9];
  const float* b1    = (const float*)d_in[10];
  const float* w2    = (const float*)d_in[11];
  const float* b2    = (const float*)d_in[12];
  float* out = (float*)d_out;

  float* ws   = (float*)d_ws;
  float* qzn  = ws;                 // [B,C,P,D] f32
  float* bufU = ws + NEL;           // tu(bf16) / cuT(bf16) / xln(f32)
  float* bufV = ws + 2 * NEL;       // tv(bf16) / cvT(bf16) / hmid(f32)
  float* accb = ws + 3 * NEL;       // m_t + m_c + m_g, then x (in place)
  u16* topicT = (u16*)(ws + 4 * NEL);
  u16* bufU16 = (u16*)bufU;
  u16* bufV16 = (u16*)bufV;

  // 1. qzn = LN(qz)
  ln_kernel<<<16384, 256, 0, stream>>>(qz, gam, bet, qzn);
  // 2-3. tu, tv (bf16)
  gemm128<4><<<1024, 256, 0, stream>>>(qzn, tuw, 1, nullptr, nullptr, nullptr, bufU16);
  gemm128<4><<<1024, 256, 0, stream>>>(qzn, tvw, 1, nullptr, nullptr, nullptr, bufV16);
  // 4. time attention -> accb (=)
  time_attn<<<512, 256, 0, stream>>>(bufU16, bufV16, qzn, accb);
  // 5-6. cu, cv (bf16, transposed layout [b,p,c,o])
  gemm128<5><<<1024, 256, 0, stream>>>(qzn, cuw, 1, nullptr, nullptr, nullptr, bufU16);
  gemm128<5><<<1024, 256, 0, stream>>>(qzn, cvw, 1, nullptr, nullptr, nullptr, bufV16);
  // 7. channel attention -> accb (+=)
  chan_attn<<<512, 256, 0, stream>>>(bufU16, bufV16, qzn, accb);
  // 8-9. topic branch -> accb (+=)
  topic_transpose<<<32, 256, 0, stream>>>(topic, topicT);
  topic_kernel<<<2048, 256, 0, stream>>>(qzn, topic, topicT, accb);
  // 10. x = 0.5*(unary + qz + accb)  (in place in accb)
  combine_kernel<<<8192, 256, 0, stream>>>(qz, unary, accb);
  // 11. xln = LN(x)
  ln_kernel<<<16384, 256, 0, stream>>>(accb, gam, bet, bufU);
  // 12. hmid = gelu(xln @ w1^T + b1)
  gemm128<2><<<1024, 256, 0, stream>>>(bufU, w1, 0, b1, nullptr, bufV, nullptr);
  // 13. out = x + hmid @ w2^T + b2  (f32)
  gemm128<3><<<1024, 256, 0, stream>>>(bufV, w2, 0, b2, accb, out, nullptr);
}

// Round 4
// 395.733 us; speedup vs baseline: 5.9520x; 1.3131x over previous
//
#include <hip/hip_runtime.h>

typedef __attribute__((ext_vector_type(8))) short short8;
typedef __attribute__((ext_vector_type(4))) float f32x4;
typedef unsigned short u16;
typedef unsigned int u32;

#define DEV static __device__ __forceinline__

// B=4, C=128, P=128, D=128, H=8, R=16, G=512
constexpr long long NEL = 4LL * 128 * 128 * 128; // 8388608 elements per [B,C,P,D] tensor

DEV float us2f(u16 u) { union { u32 i; float f; } x; x.i = (u32)u << 16; return x.f; }
DEV u16 f2us(float f) {
  union { float f; u32 i; } x; x.f = f;
  u32 r = x.i + 0x7fffu + ((x.i >> 16) & 1u);
  return (u16)(r >> 16);
}
DEV u32 pack2(float a, float b) { return (u32)f2us(a) | ((u32)f2us(b) << 16); }
DEV float gelu_f(float x) { return 0.5f * x * (1.0f + erff(x * 0.70710678118654752f)); }

// ---------------- LayerNorm (f32 -> bf16), 1 row per wave ----------------
__global__ __launch_bounds__(256) void ln_kernel(const float* __restrict__ xin,
                                                 const float* __restrict__ gw,
                                                 const float* __restrict__ bw,
                                                 u16* __restrict__ out) {
  int wv = threadIdx.x >> 6, lane = threadIdx.x & 63;
  long long row = (long long)blockIdx.x * 4 + wv;
  const float* xr = xin + row * 128;
  float2 v = *(const float2*)(xr + lane * 2);
  float a0 = v.x, a1 = v.y;
  float s = a0 + a1, q = a0 * a0 + a1 * a1;
  #pragma unroll
  for (int off = 32; off >= 1; off >>= 1) { s += __shfl_xor(s, off); q += __shfl_xor(q, off); }
  float m = s * (1.f / 128.f);
  float vv = q * (1.f / 128.f) - m * m;
  float r = rsqrtf(vv + 1e-5f);
  u32* orow = (u32*)(out + row * 128);
  orow[lane] = pack2((a0 - m) * r * gw[lane * 2] + bw[lane * 2],
                     (a1 - m) * r * gw[lane * 2 + 1] + bw[lane * 2 + 1]);
}

// ---------------- one-shot weight conversion f32 -> bf16 ----------------
// wbf layout: tuw[65536] tvw[65536] cuw[65536] cvw[65536] w1[16384] w2[16384]
__global__ __launch_bounds__(256) void convert_weights(const float* __restrict__ t0, const float* __restrict__ t1,
                                                       const float* __restrict__ t2, const float* __restrict__ t3,
                                                       const float* __restrict__ w1, const float* __restrict__ w2,
                                                       u16* __restrict__ out) {
  long long e = ((long long)blockIdx.x * 256 + threadIdx.x) * 2;
  const float* src; long long off;
  if (e < 262144) {
    int t = (int)(e >> 16);
    src = t == 0 ? t0 : t == 1 ? t1 : t == 2 ? t2 : t3;
    off = e & 65535;
  } else if (e < 278528) { src = w1; off = e - 262144; }
  else { src = w2; off = e - 278528; }
  float2 v = *(const float2*)(src + off);
  *(u32*)(out + e) = pack2(v.x, v.y);
}

// ---------------- GEMM: out[row, o] = sum_d A[row,d] * W[(b),o,d], 64 rows/block ----------------
// A, W in bf16. EPI: 2 bias+gelu bf16, 3 bias+resid f32, 4 plain bf16, 5 transposed(c<->p) bf16
template <int EPI>
__global__ __launch_bounds__(256) void gemm128(const u16* __restrict__ A, const u16* __restrict__ W,
                                               int wbatched, const float* __restrict__ bias,
                                               const float* __restrict__ resid,
                                               float* __restrict__ outf, u16* __restrict__ outb) {
  __shared__ u16 AL[64][136];
  __shared__ u16 WL[128][136];
  int rowbase = blockIdx.x * 64;
  int bb = rowbase >> 14;
  const u32* Au = (const u32*)(A + (long long)rowbase * 128);
  const u32* Wu = (const u32*)(W + (wbatched ? (long long)bb * 16384 : 0));
  int tid = threadIdx.x, l = tid & 63, w = tid >> 6;
  for (int idx = tid; idx < 4096; idx += 256)
    *(u32*)&AL[idx >> 6][(idx & 63) * 2] = Au[idx];
  for (int idx = tid; idx < 8192; idx += 256)
    *(u32*)&WL[idx >> 6][(idx & 63) * 2] = Wu[idx];
  __syncthreads();
  f32x4 acc[8];
  #pragma unroll
  for (int cf = 0; cf < 8; ++cf) acc[cf] = (f32x4){0.f, 0.f, 0.f, 0.f};
  int arow = w * 16 + (l & 15);
  int kg = (l >> 4) * 8;
  #pragma unroll
  for (int k = 0; k < 4; ++k) {
    short8 a = *(const short8*)&AL[arow][k * 32 + kg];
    #pragma unroll
    for (int cf = 0; cf < 8; ++cf) {
      short8 b = *(const short8*)&WL[cf * 16 + (l & 15)][k * 32 + kg];
      acc[cf] = __builtin_amdgcn_mfma_f32_16x16x32_bf16(a, b, acc[cf], 0, 0, 0);
    }
  }
  #pragma unroll
  for (int cf = 0; cf < 8; ++cf) {
    int col = cf * 16 + (l & 15);
    float bv = 0.f;
    if (EPI == 2 || EPI == 3) bv = bias[col];
    #pragma unroll
    for (int j = 0; j < 4; ++j) {
      int row = rowbase + w * 16 + (l >> 4) * 4 + j;
      float v = acc[cf][j];
      if (EPI == 2) {
        outb[(long long)row * 128 + col] = f2us(gelu_f(v + bv));
      } else if (EPI == 3) {
        long long o = (long long)row * 128 + col;
        outf[o] = v + bv + resid[o];
      } else if (EPI == 4) {
        outb[(long long)row * 128 + col] = f2us(v);
      } else {
        int b2i = row >> 14, c = (row >> 7) & 127, p = row & 127;
        outb[((long long)(b2i * 128 + p) * 128 + c) * 128 + col] = f2us(v);
      }
    }
  }
}

// ---------------- time attention (MFMA, sum-of-softmax over heads, single PV) ----------------
// block = (b,c); 4 waves, each owns 32 p-rows.
__global__ __launch_bounds__(256) void time_attn(const u16* __restrict__ tu,
                                                 const u16* __restrict__ tv,
                                                 const u16* __restrict__ qzn16,
                                                 float* __restrict__ accg) {
  __shared__ u16 ZT[128][136];      // qzn transposed: ZT[d][q]
  __shared__ u16 SP[4][32][136];    // per-wave summed softmax (bf16)
  int bc = blockIdx.x;
  const u16* ub = tu + (long long)bc * 16384;
  const u16* vb = tv + (long long)bc * 16384;
  const u32* zb32 = (const u32*)(qzn16 + (long long)bc * 16384);
  int tid = threadIdx.x, l = tid & 63, w = tid >> 6;
  int lo = l & 15, hi = l >> 4;
  int p0 = w * 32;
  // stage ZT (coalesced global u32 read, scalar transposed LDS write)
  for (int idx = tid; idx < 8192; idx += 256) {
    int dp = idx & 63, q = idx >> 6;
    u32 v = zb32[q * 64 + dp];
    ZT[2 * dp][q] = (u16)v;
    ZT[2 * dp + 1][q] = (u16)(v >> 16);
  }
  const short8 z8 = {0, 0, 0, 0, 0, 0, 0, 0};
  const f32x4 z4 = {0.f, 0.f, 0.f, 0.f};
  f32x4 ssum[2][8];
  #pragma unroll
  for (int i = 0; i < 2; ++i)
    #pragma unroll
    for (int cf = 0; cf < 8; ++cf) ssum[i][cf] = z4;
  bool act = hi < 2;
  for (int h = 0; h < 8; ++h) {
    int koff = h * 16 + hi * 8;  // valid only when hi<2 (k 16..31 zero-padded)
    short8 a[2];
    #pragma unroll
    for (int i = 0; i < 2; ++i)
      a[i] = act ? *(const short8*)(ub + (p0 + i * 16 + lo) * 128 + koff) : z8;
    f32x4 s[2][8];
    #pragma unroll
    for (int cf = 0; cf < 8; ++cf) {
      short8 bf = act ? *(const short8*)(vb + (cf * 16 + lo) * 128 + koff) : z8;
      #pragma unroll
      for (int i = 0; i < 2; ++i)
        s[i][cf] = __builtin_amdgcn_mfma_f32_16x16x32_bf16(a[i], bf, z4, 0, 0, 0);
    }
    float mx[2][4], rs[2][4];
    #pragma unroll
    for (int i = 0; i < 2; ++i)
      #pragma unroll
      for (int j = 0; j < 4; ++j) {
        float m = s[i][0][j];
        #pragma unroll
        for (int cf = 1; cf < 8; ++cf) m = fmaxf(m, s[i][cf][j]);
        #pragma unroll
        for (int off = 1; off <= 8; off <<= 1) m = fmaxf(m, __shfl_xor(m, off));
        mx[i][j] = m;
      }
    #pragma unroll
    for (int i = 0; i < 2; ++i)
      #pragma unroll
      for (int cf = 0; cf < 8; ++cf)
        #pragma unroll
        for (int j = 0; j < 4; ++j)
          s[i][cf][j] = __expf((s[i][cf][j] - mx[i][j]) * 0.25f);
    #pragma unroll
    for (int i = 0; i < 2; ++i)
      #pragma unroll
      for (int j = 0; j < 4; ++j) {
        float t = s[i][0][j];
        #pragma unroll
        for (int cf = 1; cf < 8; ++cf) t += s[i][cf][j];
        #pragma unroll
        for (int off = 1; off <= 8; off <<= 1) t += __shfl_xor(t, off);
        rs[i][j] = 1.f / t;
      }
    #pragma unroll
    for (int i = 0; i < 2; ++i)
      #pragma unroll
      for (int cf = 0; cf < 8; ++cf)
        #pragma unroll
        for (int j = 0; j < 4; ++j)
          ssum[i][cf][j] += s[i][cf][j] * rs[i][j];
  }
  #pragma unroll
  for (int i = 0; i < 2; ++i)
    #pragma unroll
    for (int cf = 0; cf < 8; ++cf)
      #pragma unroll
      for (int j = 0; j < 4; ++j)
        SP[w][i * 16 + hi * 4 + j][cf * 16 + lo] = f2us(ssum[i][cf][j]);
  __syncthreads();
  // PV: out[32 x 128] = SP[w] @ ZT^T, K=128
  f32x4 acc[2][8];
  #pragma unroll
  for (int i = 0; i < 2; ++i)
    #pragma unroll
    for (int dt = 0; dt < 8; ++dt) acc[i][dt] = z4;
  #pragma unroll
  for (int kk = 0; kk < 4; ++kk) {
    short8 a[2];
    #pragma unroll
    for (int i = 0; i < 2; ++i)
      a[i] = *(const short8*)&SP[w][i * 16 + lo][kk * 32 + hi * 8];
    #pragma unroll
    for (int dt = 0; dt < 8; ++dt) {
      short8 bf = *(const short8*)&ZT[dt * 16 + lo][kk * 32 + hi * 8];
      #pragma unroll
      for (int i = 0; i < 2; ++i)
        acc[i][dt] = __builtin_amdgcn_mfma_f32_16x16x32_bf16(a[i], bf, acc[i][dt], 0, 0, 0);
    }
  }
  float* og = accg + (long long)bc * 16384;
  #pragma unroll
  for (int i = 0; i < 2; ++i)
    #pragma unroll
    for (int dt = 0; dt < 8; ++dt)
      #pragma unroll
      for (int j = 0; j < 4; ++j)
        og[(p0 + i * 16 + hi * 4 + j) * 128 + dt * 16 + lo] = acc[i][dt][j] * 0.125f;
}

// ---------------- channel attention (MFMA QK, sum-of-softmax, elementwise epilogue) ----------------
__global__ __launch_bounds__(256) void chan_attn(const u16* __restrict__ cuT,
                                                 const u16* __restrict__ cvT,
                                                 const u16* __restrict__ qzn16,
                                                 float* __restrict__ accg) {
  int bp = blockIdx.x;
  int b = bp >> 7, p = bp & 127;
  const u16* ub = cuT + (long long)bp * 16384;
  const u16* vb = cvT + (long long)bp * 16384;
  int tid = threadIdx.x, l = tid & 63, w = tid >> 6;
  int lo = l & 15, hi = l >> 4;
  int c0 = w * 32;
  const short8 z8 = {0, 0, 0, 0, 0, 0, 0, 0};
  const f32x4 z4 = {0.f, 0.f, 0.f, 0.f};
  f32x4 ssum[2][8];
  #pragma unroll
  for (int i = 0; i < 2; ++i)
    #pragma unroll
    for (int cf = 0; cf < 8; ++cf) ssum[i][cf] = z4;
  bool act = hi < 2;
  for (int h = 0; h < 8; ++h) {
    int koff = h * 16 + hi * 8;
    short8 a[2];
    #pragma unroll
    for (int i = 0; i < 2; ++i)
      a[i] = act ? *(const short8*)(ub + (c0 + i * 16 + lo) * 128 + koff) : z8;
    f32x4 s[2][8];
    #pragma unroll
    for (int cf = 0; cf < 8; ++cf) {
      short8 bf = act ? *(const short8*)(vb + (cf * 16 + lo) * 128 + koff) : z8;
      #pragma unroll
      for (int i = 0; i < 2; ++i)
        s[i][cf] = __builtin_amdgcn_mfma_f32_16x16x32_bf16(a[i], bf, z4, 0, 0, 0);
    }
    float mx[2][4], rs[2][4];
    #pragma unroll
    for (int i = 0; i < 2; ++i)
      #pragma unroll
      for (int j = 0; j < 4; ++j) {
        float m = s[i][0][j];
        #pragma unroll
        for (int cf = 1; cf < 8; ++cf) m = fmaxf(m, s[i][cf][j]);
        #pragma unroll
        for (int off = 1; off <= 8; off <<= 1) m = fmaxf(m, __shfl_xor(m, off));
        mx[i][j] = m;
      }
    #pragma unroll
    for (int i = 0; i < 2; ++i)
      #pragma unroll
      for (int cf = 0; cf < 8; ++cf)
        #pragma unroll
        for (int j = 0; j < 4; ++j)
          s[i][cf][j] = __expf((s[i][cf][j] - mx[i][j]) * 0.25f);
    #pragma unroll
    for (int i = 0; i < 2; ++i)
      #pragma unroll
      for (int j = 0; j < 4; ++j) {
        float t = s[i][0][j];
        #pragma unroll
        for (int cf = 1; cf < 8; ++cf) t += s[i][cf][j];
        #pragma unroll
        for (int off = 1; off <= 8; off <<= 1) t += __shfl_xor(t, off);
        rs[i][j] = 1.f / t;
      }
    #pragma unroll
    for (int i = 0; i < 2; ++i)
      #pragma unroll
      for (int cf = 0; cf < 8; ++cf)
        #pragma unroll
        for (int j = 0; j < 4; ++j)
          ssum[i][cf][j] += s[i][cf][j] * rs[i][j];
  }
  const u16* zb = qzn16 + (long long)b * 2097152;
  float* ob = accg + (long long)b * 2097152;
  #pragma unroll
  for (int i = 0; i < 2; ++i)
    #pragma unroll
    for (int cf = 0; cf < 8; ++cf)
      #pragma unroll
      for (int j = 0; j < 4; ++j) {
        int c = c0 + i * 16 + hi * 4 + j;
        int o = cf * 16 + lo;
        long long off = ((long long)c * 128 + p) * 128 + o;
        ob[off] += ssum[i][cf][j] * 0.125f * us2f(zb[off]);
      }
}

// ---------------- topic prep: topicB[g][d] bf16, topicT[d][g] bf16 ----------------
__global__ __launch_bounds__(256) void topic_transpose(const float* __restrict__ topic,
                                                       u16* __restrict__ topicB, u16* __restrict__ topicT) {
  __shared__ u16 tile[64][136];
  int b = blockIdx.x >> 3, gc = blockIdx.x & 7;
  const float* tb = topic + (long long)b * 65536;
  u16* tBo = topicB + (long long)b * 65536;
  for (int idx = threadIdx.x; idx < 64 * 64; idx += 256) {
    int g = idx >> 6, d2 = idx & 63;
    const float2 v = *(const float2*)(tb + (long long)(gc * 64 + g) * 128 + d2 * 2);
    u32 pv = pack2(v.x, v.y);
    *(u32*)&tile[g][d2 * 2] = pv;
    *(u32*)(tBo + (long long)(gc * 64 + g) * 128 + d2 * 2) = pv;
  }
  __syncthreads();
  u16* to = topicT + (long long)b * 65536;
  for (int idx = threadIdx.x; idx < 128 * 64; idx += 256) {
    int d = idx >> 6, g = idx & 63;
    to[d * 512 + gc * 64 + g] = tile[g][d];
  }
}

// ---------------- topic branch: 32 rows/block, MFMA both phases, B-operands from L2 ----------------
__global__ __launch_bounds__(256) void topic_kernel(const u16* __restrict__ qzn16,
                                                    const u16* __restrict__ topicB,
                                                    const u16* __restrict__ topicT,
                                                    float* __restrict__ accg) {
  __shared__ u16 AL[32][136];
  __shared__ u16 QG[32][520];
  __shared__ float redsum[4][32];
  int rowbase = blockIdx.x * 32;
  int b = rowbase >> 14;
  const u16* tB = topicB + (long long)b * 65536;
  const u16* tT = topicT + (long long)b * 65536;
  int tid = threadIdx.x, l = tid & 63, w = tid >> 6;
  int lo = l & 15, hi = l >> 4;
  const u32* asrc = (const u32*)(qzn16 + (long long)rowbase * 128);
  for (int idx = tid; idx < 2048; idx += 256)
    *(u32*)&AL[idx >> 6][(idx & 63) * 2] = asrc[idx];
  __syncthreads();
  const f32x4 z4 = {0.f, 0.f, 0.f, 0.f};
  // Phase A: qg = relu(qzn @ topicB^T); wave w owns cols w*16 of each 64-chunk
  float rsum[2][4] = {{0.f,0.f,0.f,0.f},{0.f,0.f,0.f,0.f}};
  #pragma unroll
  for (int gc = 0; gc < 8; ++gc) {
    f32x4 pa[2] = {z4, z4};
    #pragma unroll
    for (int k = 0; k < 4; ++k) {
      short8 bb = *(const short8*)(tB + (long long)(gc * 64 + w * 16 + lo) * 128 + k * 32 + hi * 8);
      #pragma unroll
      for (int i = 0; i < 2; ++i) {
        short8 a = *(const short8*)&AL[i * 16 + lo][k * 32 + hi * 8];
        pa[i] = __builtin_amdgcn_mfma_f32_16x16x32_bf16(a, bb, pa[i], 0, 0, 0);
      }
    }
    #pragma unroll
    for (int i = 0; i < 2; ++i)
      #pragma unroll
      for (int j = 0; j < 4; ++j) {
        float v = fmaxf(pa[i][j], 0.f);
        QG[i * 16 + hi * 4 + j][gc * 64 + w * 16 + lo] = f2us(v);
        rsum[i][j] += v;
      }
  }
  #pragma unroll
  for (int i = 0; i < 2; ++i)
    #pragma unroll
    for (int j = 0; j < 4; ++j) {
      float t = rsum[i][j];
      #pragma unroll
      for (int off = 1; off <= 8; off <<= 1) t += __shfl_xor(t, off);
      rsum[i][j] = t;
    }
  if (lo == 0) {
    #pragma unroll
    for (int i = 0; i < 2; ++i)
      #pragma unroll
      for (int j = 0; j < 4; ++j)
        redsum[w][i * 16 + hi * 4 + j] = rsum[i][j];
  }
  __syncthreads();
  float inv[2][4];
  #pragma unroll
  for (int i = 0; i < 2; ++i)
    #pragma unroll
    for (int j = 0; j < 4; ++j) {
      int row = i * 16 + hi * 4 + j;
      float s = redsum[0][row] + redsum[1][row] + redsum[2][row] + redsum[3][row];
      inv[i][j] = 1.f / fmaxf(s, 1e-6f);
    }
  // Phase B: m_g = qg @ topicT^T (K=512); wave w owns out cols w*32..w*32+31
  f32x4 ba[2][2] = {{z4, z4}, {z4, z4}};
  #pragma unroll
  for (int kc = 0; kc < 16; ++kc) {
    short8 a[2];
    #pragma unroll
    for (int i = 0; i < 2; ++i)
      a[i] = *(const short8*)&QG[i * 16 + lo][kc * 32 + hi * 8];
    #pragma unroll
    for (int cf = 0; cf < 2; ++cf) {
      short8 bb = *(const short8*)(tT + (long long)(w * 32 + cf * 16 + lo) * 512 + kc * 32 + hi * 8);
      #pragma unroll
      for (int i = 0; i < 2; ++i)
        ba[i][cf] = __builtin_amdgcn_mfma_f32_16x16x32_bf16(a[i], bb, ba[i][cf], 0, 0, 0);
    }
  }
  #pragma unroll
  for (int i = 0; i < 2; ++i)
    #pragma unroll
    for (int cf = 0; cf < 2; ++cf)
      #pragma unroll
      for (int j = 0; j < 4; ++j) {
        long long o = (long long)(rowbase + i * 16 + hi * 4 + j) * 128 + w * 32 + cf * 16 + lo;
        accg[o] += ba[i][cf][j] * inv[i][j];
      }
}

// ---------------- combine (in place): acc = 0.5*(unary + qz + acc) ----------------
__global__ __launch_bounds__(256) void combine_kernel(const float* __restrict__ qz, const float* __restrict__ un,
                                                      float* __restrict__ acc) {
  long long i = ((long long)blockIdx.x * 256 + threadIdx.x) * 4;
  float4 q = *(const float4*)(qz + i);
  float4 u = *(const float4*)(un + i);
  float4 a = *(const float4*)(acc + i);
  float4 r;
  r.x = 0.5f * (q.x + u.x + a.x);
  r.y = 0.5f * (q.y + u.y + a.y);
  r.z = 0.5f * (q.z + u.z + a.z);
  r.w = 0.5f * (q.w + u.w + a.w);
  *(float4*)(acc + i) = r;
}

extern "C" void kernel_launch(void* const* d_in, const int* in_sizes, int n_in,
                              void* d_out, int out_size, void* d_ws, size_t ws_size,
                              hipStream_t stream) {
  const float* qz    = (const float*)d_in[0];
  const float* unary = (const float*)d_in[1];
  const float* tuw   = (const float*)d_in[2];
  const float* tvw   = (const float*)d_in[3];
  const float* cuw   = (const float*)d_in[4];
  const float* cvw   = (const float*)d_in[5];
  const float* topic = (const float*)d_in[6];
  const float* gam   = (const float*)d_in[7];
  const float* bet   = (const float*)d_in[8];
  const float* w1    = (const float*)d_in[9];
  const float* b1    = (const float*)d_in[10];
  const float* w2    = (const float*)d_in[11];
  const float* b2    = (const float*)d_in[12];
  float* out = (float*)d_out;

  char* base = (char*)d_ws;
  u16*   qzn16  = (u16*)base;                    // NEL bf16
  float* accb   = (float*)(base + NEL * 2);      // NEL f32
  u16*   bufU16 = (u16*)(base + NEL * 6);        // NEL bf16 (tu / cuT / xln)
  u16*   bufV16 = (u16*)(base + NEL * 8);        // NEL bf16 (tv / cvT / hmid)
  u16*   wbf    = (u16*)(base + NEL * 10);       // 294912 bf16 weights
  u16*   topicB = wbf + 294912;                  // 262144
  u16*   topicT = topicB + 262144;               // 262144

  // prep: weights + topic to bf16
  convert_weights<<<576, 256, 0, stream>>>(tuw, tvw, cuw, cvw, w1, w2, wbf);
  topic_transpose<<<32, 256, 0, stream>>>(topic, topicB, topicT);
  // 1. qzn = LN(qz) (bf16)
  ln_kernel<<<16384, 256, 0, stream>>>(qz, gam, bet, qzn16);
  // 2-3. tu, tv (bf16)
  gemm128<4><<<1024, 256, 0, stream>>>(qzn16, wbf,         1, nullptr, nullptr, nullptr, bufU16);
  gemm128<4><<<1024, 256, 0, stream>>>(qzn16, wbf + 65536, 1, nullptr, nullptr, nullptr, bufV16);
  // 4. time attention -> accb (=)
  time_attn<<<512, 256, 0, stream>>>(bufU16, bufV16, qzn16, accb);
  // 5-6. cu, cv (bf16, transposed layout [b,p,c,o])
  gemm128<5><<<1024, 256, 0, stream>>>(qzn16, wbf + 131072, 1, nullptr, nullptr, nullptr, bufU16);
  gemm128<5><<<1024, 256, 0, stream>>>(qzn16, wbf + 196608, 1, nullptr, nullptr, nullptr, bufV16);
  // 7. channel attention -> accb (+=)
  chan_attn<<<512, 256, 0, stream>>>(bufU16, bufV16, qzn16, accb);
  // 8. topic branch -> accb (+=)
  topic_kernel<<<2048, 256, 0, stream>>>(qzn16, topicB, topicT, accb);
  // 9. x = 0.5*(unary + qz + accb)  (in place in accb)
  combine_kernel<<<8192, 256, 0, stream>>>(qz, unary, accb);
  // 10. xln = LN(x) (bf16)
  ln_kernel<<<16384, 256, 0, stream>>>(accb, gam, bet, bufU16);
  // 11. hmid = gelu(xln @ w1^T + b1) (bf16)
  gemm128<2><<<1024, 256, 0, stream>>>(bufU16, wbf + 262144, 0, b1, nullptr, nullptr, bufV16);
  // 12. out = x + hmid @ w2^T + b2  (f32)
  gemm128<3><<<1024, 256, 0, stream>>>(bufV16, wbf + 278528, 0, b2, accb, out, nullptr);
}

// Round 5
// 394.316 us; speedup vs baseline: 5.9734x; 1.0036x over previous
//
#include <hip/hip_runtime.h>

typedef __attribute__((ext_vector_type(8))) short short8;
typedef __attribute__((ext_vector_type(4))) float f32x4;
typedef unsigned short u16;
typedef unsigned int u32;

#define DEV static __device__ __forceinline__

// B=4, C=128, P=128, D=128, H=8, R=16, G=512
constexpr long long NEL = 4LL * 128 * 128 * 128;

DEV float us2f(u16 u) { union { u32 i; float f; } x; x.i = (u32)u << 16; return x.f; }
DEV u16 f2us(float f) {
  union { float f; u32 i; } x; x.f = f;
  u32 r = x.i + 0x7fffu + ((x.i >> 16) & 1u);
  return (u16)(r >> 16);
}
DEV u32 pack2(float a, float b) { return (u32)f2us(a) | ((u32)f2us(b) << 16); }
DEV float gelu_f(float x) { return 0.5f * x * (1.0f + erff(x * 0.70710678118654752f)); }

// ---------------- LayerNorm (f32 -> bf16), 1 row per wave ----------------
__global__ __launch_bounds__(256) void ln_kernel(const float* __restrict__ xin,
                                                 const float* __restrict__ gw,
                                                 const float* __restrict__ bw,
                                                 u16* __restrict__ out) {
  int wv = threadIdx.x >> 6, lane = threadIdx.x & 63;
  long long row = (long long)blockIdx.x * 4 + wv;
  const float* xr = xin + row * 128;
  float2 v = *(const float2*)(xr + lane * 2);
  float a0 = v.x, a1 = v.y;
  float s = a0 + a1, q = a0 * a0 + a1 * a1;
  #pragma unroll
  for (int off = 32; off >= 1; off >>= 1) { s += __shfl_xor(s, off); q += __shfl_xor(q, off); }
  float m = s * (1.f / 128.f);
  float vv = q * (1.f / 128.f) - m * m;
  float r = rsqrtf(vv + 1e-5f);
  u32* orow = (u32*)(out + row * 128);
  orow[lane] = pack2((a0 - m) * r * gw[lane * 2] + bw[lane * 2],
                     (a1 - m) * r * gw[lane * 2 + 1] + bw[lane * 2 + 1]);
}

// ---------------- one-shot weight conversion f32 -> bf16 ----------------
__global__ __launch_bounds__(256) void convert_weights(const float* __restrict__ t0, const float* __restrict__ t1,
                                                       const float* __restrict__ t2, const float* __restrict__ t3,
                                                       const float* __restrict__ w1, const float* __restrict__ w2,
                                                       u16* __restrict__ out) {
  long long e = ((long long)blockIdx.x * 256 + threadIdx.x) * 2;
  const float* src; long long off;
  if (e < 262144) {
    int t = (int)(e >> 16);
    src = t == 0 ? t0 : t == 1 ? t1 : t == 2 ? t2 : t3;
    off = e & 65535;
  } else if (e < 278528) { src = w1; off = e - 262144; }
  else { src = w2; off = e - 278528; }
  float2 v = *(const float2*)(src + off);
  *(u32*)(out + e) = pack2(v.x, v.y);
}

// ---------------- single GEMM (MLP): EPI 2 bias+gelu bf16, 3 bias+resid f32 ----------------
template <int EPI>
__global__ __launch_bounds__(256) void gemm128(const u16* __restrict__ A, const u16* __restrict__ W,
                                               const float* __restrict__ bias,
                                               const float* __restrict__ resid,
                                               float* __restrict__ outf, u16* __restrict__ outb) {
  __shared__ u16 AL[64][136];
  __shared__ u16 WL[128][136];
  int rowbase = blockIdx.x * 64;
  const u32* Au = (const u32*)(A + (long long)rowbase * 128);
  const u32* Wu = (const u32*)W;
  int tid = threadIdx.x, l = tid & 63, w = tid >> 6;
  for (int idx = tid; idx < 4096; idx += 256)
    *(u32*)&AL[idx >> 6][(idx & 63) * 2] = Au[idx];
  for (int idx = tid; idx < 8192; idx += 256)
    *(u32*)&WL[idx >> 6][(idx & 63) * 2] = Wu[idx];
  __syncthreads();
  f32x4 acc[8];
  #pragma unroll
  for (int cf = 0; cf < 8; ++cf) acc[cf] = (f32x4){0.f, 0.f, 0.f, 0.f};
  int arow = w * 16 + (l & 15);
  int kg = (l >> 4) * 8;
  #pragma unroll
  for (int k = 0; k < 4; ++k) {
    short8 a = *(const short8*)&AL[arow][k * 32 + kg];
    #pragma unroll
    for (int cf = 0; cf < 8; ++cf) {
      short8 b = *(const short8*)&WL[cf * 16 + (l & 15)][k * 32 + kg];
      acc[cf] = __builtin_amdgcn_mfma_f32_16x16x32_bf16(a, b, acc[cf], 0, 0, 0);
    }
  }
  #pragma unroll
  for (int cf = 0; cf < 8; ++cf) {
    int col = cf * 16 + (l & 15);
    float bv = bias[col];
    #pragma unroll
    for (int j = 0; j < 4; ++j) {
      int row = rowbase + w * 16 + (l >> 4) * 4 + j;
      float v = acc[cf][j];
      if (EPI == 2) {
        outb[(long long)row * 128 + col] = f2us(gelu_f(v + bv));
      } else {
        long long o = (long long)row * 128 + col;
        outf[o] = v + bv + resid[o];
      }
    }
  }
}

// ---------------- dual GEMM: two weights, shared A staging ----------------
// EPI: 4 plain bf16, 5 transposed(c<->p) bf16. W batched per b.
template <int EPI>
__global__ __launch_bounds__(256) void gemm_dual(const u16* __restrict__ A,
                                                 const u16* __restrict__ W0, const u16* __restrict__ W1,
                                                 u16* __restrict__ out0, u16* __restrict__ out1) {
  __shared__ u16 AL[64][136];
  __shared__ u16 WL[128][136];
  int rowbase = blockIdx.x * 64;
  int bb = rowbase >> 14;
  const u32* Au = (const u32*)(A + (long long)rowbase * 128);
  int tid = threadIdx.x, l = tid & 63, w = tid >> 6;
  for (int idx = tid; idx < 4096; idx += 256)
    *(u32*)&AL[idx >> 6][(idx & 63) * 2] = Au[idx];
  int arow = w * 16 + (l & 15);
  int kg = (l >> 4) * 8;
  #pragma unroll
  for (int widx = 0; widx < 2; ++widx) {
    const u32* Wu = (const u32*)((widx ? W1 : W0) + (long long)bb * 16384);
    for (int idx = tid; idx < 8192; idx += 256)
      *(u32*)&WL[idx >> 6][(idx & 63) * 2] = Wu[idx];
    __syncthreads();
    f32x4 acc[8];
    #pragma unroll
    for (int cf = 0; cf < 8; ++cf) acc[cf] = (f32x4){0.f, 0.f, 0.f, 0.f};
    #pragma unroll
    for (int k = 0; k < 4; ++k) {
      short8 a = *(const short8*)&AL[arow][k * 32 + kg];
      #pragma unroll
      for (int cf = 0; cf < 8; ++cf) {
        short8 b = *(const short8*)&WL[cf * 16 + (l & 15)][k * 32 + kg];
        acc[cf] = __builtin_amdgcn_mfma_f32_16x16x32_bf16(a, b, acc[cf], 0, 0, 0);
      }
    }
    u16* ob = widx ? out1 : out0;
    #pragma unroll
    for (int cf = 0; cf < 8; ++cf) {
      int col = cf * 16 + (l & 15);
      #pragma unroll
      for (int j = 0; j < 4; ++j) {
        int row = rowbase + w * 16 + (l >> 4) * 4 + j;
        float v = acc[cf][j];
        if (EPI == 4) {
          ob[(long long)row * 128 + col] = f2us(v);
        } else {
          int b2i = row >> 14, c = (row >> 7) & 127, p = row & 127;
          ob[((long long)(b2i * 128 + p) * 128 + c) * 128 + col] = f2us(v);
        }
      }
    }
    __syncthreads();  // before restaging WL
  }
}

// ---------------- time attention (MFMA, sum-of-softmax over heads, single PV) ----------------
// block = (b,c); 4 waves, each owns 32 p-rows. VB and SP alias one LDS buffer.
__global__ __launch_bounds__(256) void time_attn(const u16* __restrict__ tu,
                                                 const u16* __restrict__ tv,
                                                 const u16* __restrict__ qzn16,
                                                 float* __restrict__ accg) {
  __shared__ u16 ZT[128][136];   // qzn transposed: ZT[d][q]
  __shared__ u16 UB[17408];      // VB[128][136] during QK; SP[4][32][136] during PV
  #define VB_(r, c) UB[(r) * 136 + (c)]
  #define SP_(wv, r, c) UB[((wv) * 32 + (r)) * 136 + (c)]
  int bc = blockIdx.x;
  const u16* ub = tu + (long long)bc * 16384;
  const u32* vb32 = (const u32*)(tv + (long long)bc * 16384);
  const u32* zb32 = (const u32*)(qzn16 + (long long)bc * 16384);
  int tid = threadIdx.x, l = tid & 63, w = tid >> 6;
  int lo = l & 15, hi = l >> 4;
  int p0 = w * 32;
  for (int idx = tid; idx < 8192; idx += 256) {
    int dp = idx & 63, q = idx >> 6;
    u32 v = zb32[idx];
    ZT[2 * dp][q] = (u16)v;
    ZT[2 * dp + 1][q] = (u16)(v >> 16);
  }
  for (int idx = tid; idx < 8192; idx += 256)
    *(u32*)&VB_(idx >> 6, (idx & 63) * 2) = vb32[idx];
  __syncthreads();
  const short8 z8 = {0, 0, 0, 0, 0, 0, 0, 0};
  const f32x4 z4 = {0.f, 0.f, 0.f, 0.f};
  f32x4 ssum[2][8];
  #pragma unroll
  for (int i = 0; i < 2; ++i)
    #pragma unroll
    for (int cf = 0; cf < 8; ++cf) ssum[i][cf] = z4;
  bool act = hi < 2;
  for (int h = 0; h < 8; ++h) {
    int koff = h * 16 + hi * 8;  // valid only when hi<2 (k 16..31 zero-padded)
    short8 a[2];
    #pragma unroll
    for (int i = 0; i < 2; ++i)
      a[i] = act ? *(const short8*)(ub + (p0 + i * 16 + lo) * 128 + koff) : z8;
    f32x4 s[2][8];
    #pragma unroll
    for (int cf = 0; cf < 8; ++cf) {
      short8 bf = act ? *(const short8*)&VB_(cf * 16 + lo, koff) : z8;
      #pragma unroll
      for (int i = 0; i < 2; ++i)
        s[i][cf] = __builtin_amdgcn_mfma_f32_16x16x32_bf16(a[i], bf, z4, 0, 0, 0);
    }
    float mx[2][4], rs[2][4];
    #pragma unroll
    for (int i = 0; i < 2; ++i)
      #pragma unroll
      for (int j = 0; j < 4; ++j) {
        float m = s[i][0][j];
        #pragma unroll
        for (int cf = 1; cf < 8; ++cf) m = fmaxf(m, s[i][cf][j]);
        #pragma unroll
        for (int off = 1; off <= 8; off <<= 1) m = fmaxf(m, __shfl_xor(m, off));
        mx[i][j] = m;
      }
    #pragma unroll
    for (int i = 0; i < 2; ++i)
      #pragma unroll
      for (int cf = 0; cf < 8; ++cf)
        #pragma unroll
        for (int j = 0; j < 4; ++j)
          s[i][cf][j] = __expf((s[i][cf][j] - mx[i][j]) * 0.25f);
    #pragma unroll
    for (int i = 0; i < 2; ++i)
      #pragma unroll
      for (int j = 0; j < 4; ++j) {
        float t = s[i][0][j];
        #pragma unroll
        for (int cf = 1; cf < 8; ++cf) t += s[i][cf][j];
        #pragma unroll
        for (int off = 1; off <= 8; off <<= 1) t += __shfl_xor(t, off);
        rs[i][j] = 1.f / t;
      }
    #pragma unroll
    for (int i = 0; i < 2; ++i)
      #pragma unroll
      for (int cf = 0; cf < 8; ++cf)
        #pragma unroll
        for (int j = 0; j < 4; ++j)
          ssum[i][cf][j] += s[i][cf][j] * rs[i][j];
  }
  __syncthreads();  // all VB reads done before SP overwrites the buffer
  #pragma unroll
  for (int i = 0; i < 2; ++i)
    #pragma unroll
    for (int cf = 0; cf < 8; ++cf)
      #pragma unroll
      for (int j = 0; j < 4; ++j)
        SP_(w, i * 16 + hi * 4 + j, cf * 16 + lo) = f2us(ssum[i][cf][j]);
  __syncthreads();
  // PV: out[32 x 128] = SP[w] @ ZT^T, K=128
  f32x4 acc[2][8];
  #pragma unroll
  for (int i = 0; i < 2; ++i)
    #pragma unroll
    for (int dt = 0; dt < 8; ++dt) acc[i][dt] = z4;
  #pragma unroll
  for (int kk = 0; kk < 4; ++kk) {
    short8 a[2];
    #pragma unroll
    for (int i = 0; i < 2; ++i)
      a[i] = *(const short8*)&SP_(w, i * 16 + lo, kk * 32 + hi * 8);
    #pragma unroll
    for (int dt = 0; dt < 8; ++dt) {
      short8 bf = *(const short8*)&ZT[dt * 16 + lo][kk * 32 + hi * 8];
      #pragma unroll
      for (int i = 0; i < 2; ++i)
        acc[i][dt] = __builtin_amdgcn_mfma_f32_16x16x32_bf16(a[i], bf, acc[i][dt], 0, 0, 0);
    }
  }
  float* og = accg + (long long)bc * 16384;
  #pragma unroll
  for (int i = 0; i < 2; ++i)
    #pragma unroll
    for (int dt = 0; dt < 8; ++dt)
      #pragma unroll
      for (int j = 0; j < 4; ++j)
        og[(p0 + i * 16 + hi * 4 + j) * 128 + dt * 16 + lo] = acc[i][dt][j] * 0.125f;
  #undef VB_
  #undef SP_
}

// ---------------- channel attention (MFMA QK from LDS, elementwise epilogue) ----------------
__global__ __launch_bounds__(256) void chan_attn(const u16* __restrict__ cuT,
                                                 const u16* __restrict__ cvT,
                                                 const u16* __restrict__ qzn16,
                                                 float* __restrict__ accg) {
  __shared__ u16 VB[128][136];
  int bp = blockIdx.x;
  int b = bp >> 7, p = bp & 127;
  const u16* ub = cuT + (long long)bp * 16384;
  const u32* vb32 = (const u32*)(cvT + (long long)bp * 16384);
  int tid = threadIdx.x, l = tid & 63, w = tid >> 6;
  int lo = l & 15, hi = l >> 4;
  int c0 = w * 32;
  for (int idx = tid; idx < 8192; idx += 256)
    *(u32*)&VB[idx >> 6][(idx & 63) * 2] = vb32[idx];
  __syncthreads();
  const short8 z8 = {0, 0, 0, 0, 0, 0, 0, 0};
  const f32x4 z4 = {0.f, 0.f, 0.f, 0.f};
  f32x4 ssum[2][8];
  #pragma unroll
  for (int i = 0; i < 2; ++i)
    #pragma unroll
    for (int cf = 0; cf < 8; ++cf) ssum[i][cf] = z4;
  bool act = hi < 2;
  for (int h = 0; h < 8; ++h) {
    int koff = h * 16 + hi * 8;
    short8 a[2];
    #pragma unroll
    for (int i = 0; i < 2; ++i)
      a[i] = act ? *(const short8*)(ub + (c0 + i * 16 + lo) * 128 + koff) : z8;
    f32x4 s[2][8];
    #pragma unroll
    for (int cf = 0; cf < 8; ++cf) {
      short8 bf = act ? *(const short8*)&VB[cf * 16 + lo][koff] : z8;
      #pragma unroll
      for (int i = 0; i < 2; ++i)
        s[i][cf] = __builtin_amdgcn_mfma_f32_16x16x32_bf16(a[i], bf, z4, 0, 0, 0);
    }
    float mx[2][4], rs[2][4];
    #pragma unroll
    for (int i = 0; i < 2; ++i)
      #pragma unroll
      for (int j = 0; j < 4; ++j) {
        float m = s[i][0][j];
        #pragma unroll
        for (int cf = 1; cf < 8; ++cf) m = fmaxf(m, s[i][cf][j]);
        #pragma unroll
        for (int off = 1; off <= 8; off <<= 1) m = fmaxf(m, __shfl_xor(m, off));
        mx[i][j] = m;
      }
    #pragma unroll
    for (int i = 0; i < 2; ++i)
      #pragma unroll
      for (int cf = 0; cf < 8; ++cf)
        #pragma unroll
        for (int j = 0; j < 4; ++j)
          s[i][cf][j] = __expf((s[i][cf][j] - mx[i][j]) * 0.25f);
    #pragma unroll
    for (int i = 0; i < 2; ++i)
      #pragma unroll
      for (int j = 0; j < 4; ++j) {
        float t = s[i][0][j];
        #pragma unroll
        for (int cf = 1; cf < 8; ++cf) t += s[i][cf][j];
        #pragma unroll
        for (int off = 1; off <= 8; off <<= 1) t += __shfl_xor(t, off);
        rs[i][j] = 1.f / t;
      }
    #pragma unroll
    for (int i = 0; i < 2; ++i)
      #pragma unroll
      for (int cf = 0; cf < 8; ++cf)
        #pragma unroll
        for (int j = 0; j < 4; ++j)
          ssum[i][cf][j] += s[i][cf][j] * rs[i][j];
  }
  const u16* zb = qzn16 + (long long)b * 2097152;
  float* ob = accg + (long long)b * 2097152;
  #pragma unroll
  for (int i = 0; i < 2; ++i)
    #pragma unroll
    for (int cf = 0; cf < 8; ++cf)
      #pragma unroll
      for (int j = 0; j < 4; ++j) {
        int c = c0 + i * 16 + hi * 4 + j;
        int o = cf * 16 + lo;
        long long off = ((long long)c * 128 + p) * 128 + o;
        ob[off] += ssum[i][cf][j] * 0.125f * us2f(zb[off]);
      }
}

// ---------------- topic prep: topicB[g][d] bf16, topicT[d][g] bf16 ----------------
__global__ __launch_bounds__(256) void topic_transpose(const float* __restrict__ topic,
                                                       u16* __restrict__ topicB, u16* __restrict__ topicT) {
  __shared__ u16 tile[64][136];
  int b = blockIdx.x >> 3, gc = blockIdx.x & 7;
  const float* tb = topic + (long long)b * 65536;
  u16* tBo = topicB + (long long)b * 65536;
  for (int idx = threadIdx.x; idx < 64 * 64; idx += 256) {
    int g = idx >> 6, d2 = idx & 63;
    const float2 v = *(const float2*)(tb + (long long)(gc * 64 + g) * 128 + d2 * 2);
    u32 pv = pack2(v.x, v.y);
    *(u32*)&tile[g][d2 * 2] = pv;
    *(u32*)(tBo + (long long)(gc * 64 + g) * 128 + d2 * 2) = pv;
  }
  __syncthreads();
  u16* to = topicT + (long long)b * 65536;
  for (int idx = threadIdx.x; idx < 128 * 64; idx += 256) {
    int d = idx >> 6, g = idx & 63;
    to[d * 512 + gc * 64 + g] = tile[g][d];
  }
}

// ---------------- topic branch + combine + LN2 (fused) ----------------
// 32 rows/block; adds m_g, forms x = 0.5*(un+qz+acc), writes x (f32, in place in accg)
// and xln = LN(x) (bf16) for the MLP.
__global__ __launch_bounds__(256) void topic_fuse(const u16* __restrict__ qzn16,
                                                  const u16* __restrict__ topicB,
                                                  const u16* __restrict__ topicT,
                                                  const float* __restrict__ qz,
                                                  const float* __restrict__ un,
                                                  const float* __restrict__ gam,
                                                  const float* __restrict__ bet,
                                                  float* __restrict__ accg,
                                                  u16* __restrict__ xln) {
  __shared__ u16 AL[32][136];
  __shared__ u16 QG[32][520];
  __shared__ float redL[4][32];
  __shared__ float redS[4][32];
  __shared__ float redQ[4][32];
  int rowbase = blockIdx.x * 32;
  int b = rowbase >> 14;
  const u16* tB = topicB + (long long)b * 65536;
  const u16* tT = topicT + (long long)b * 65536;
  int tid = threadIdx.x, l = tid & 63, w = tid >> 6;
  int lo = l & 15, hi = l >> 4;
  const u32* asrc = (const u32*)(qzn16 + (long long)rowbase * 128);
  for (int idx = tid; idx < 2048; idx += 256)
    *(u32*)&AL[idx >> 6][(idx & 63) * 2] = asrc[idx];
  __syncthreads();
  const f32x4 z4 = {0.f, 0.f, 0.f, 0.f};
  // Phase A: qg = relu(qzn @ topicB^T); wave w owns cols w*16 of each 64-chunk
  float rsum[2][4] = {{0.f, 0.f, 0.f, 0.f}, {0.f, 0.f, 0.f, 0.f}};
  #pragma unroll
  for (int gc = 0; gc < 8; ++gc) {
    f32x4 pa[2] = {z4, z4};
    #pragma unroll
    for (int k = 0; k < 4; ++k) {
      short8 bb = *(const short8*)(tB + (long long)(gc * 64 + w * 16 + lo) * 128 + k * 32 + hi * 8);
      #pragma unroll
      for (int i = 0; i < 2; ++i) {
        short8 a = *(const short8*)&AL[i * 16 + lo][k * 32 + hi * 8];
        pa[i] = __builtin_amdgcn_mfma_f32_16x16x32_bf16(a, bb, pa[i], 0, 0, 0);
      }
    }
    #pragma unroll
    for (int i = 0; i < 2; ++i)
      #pragma unroll
      for (int j = 0; j < 4; ++j) {
        float v = fmaxf(pa[i][j], 0.f);
        QG[i * 16 + hi * 4 + j][gc * 64 + w * 16 + lo] = f2us(v);
        rsum[i][j] += v;
      }
  }
  #pragma unroll
  for (int i = 0; i < 2; ++i)
    #pragma unroll
    for (int j = 0; j < 4; ++j) {
      float t = rsum[i][j];
      #pragma unroll
      for (int off = 1; off <= 8; off <<= 1) t += __shfl_xor(t, off);
      rsum[i][j] = t;
    }
  if (lo == 0) {
    #pragma unroll
    for (int i = 0; i < 2; ++i)
      #pragma unroll
      for (int j = 0; j < 4; ++j)
        redL[w][i * 16 + hi * 4 + j] = rsum[i][j];
  }
  __syncthreads();
  float inv[2][4];
  #pragma unroll
  for (int i = 0; i < 2; ++i)
    #pragma unroll
    for (int j = 0; j < 4; ++j) {
      int row = i * 16 + hi * 4 + j;
      float s = redL[0][row] + redL[1][row] + redL[2][row] + redL[3][row];
      inv[i][j] = 1.f / fmaxf(s, 1e-6f);
    }
  // Phase B: m_g = qg @ topicT^T (K=512); wave w owns out cols w*32..w*32+31
  f32x4 ba[2][2] = {{z4, z4}, {z4, z4}};
  #pragma unroll
  for (int kc = 0; kc < 16; ++kc) {
    short8 a[2];
    #pragma unroll
    for (int i = 0; i < 2; ++i)
      a[i] = *(const short8*)&QG[i * 16 + lo][kc * 32 + hi * 8];
    #pragma unroll
    for (int cf = 0; cf < 2; ++cf) {
      short8 bb = *(const short8*)(tT + (long long)(w * 32 + cf * 16 + lo) * 512 + kc * 32 + hi * 8);
      #pragma unroll
      for (int i = 0; i < 2; ++i)
        ba[i][cf] = __builtin_amdgcn_mfma_f32_16x16x32_bf16(a[i], bb, ba[i][cf], 0, 0, 0);
    }
  }
  // Epilogue: x = 0.5*(qz + un + acc + m_g); accg <- x; then row LN -> xln (bf16)
  float gv[2], bv[2];
  #pragma unroll
  for (int cf = 0; cf < 2; ++cf) {
    int col = w * 32 + cf * 16 + lo;
    gv[cf] = gam[col];
    bv[cf] = bet[col];
  }
  float xv[2][2][4];
  #pragma unroll
  for (int i = 0; i < 2; ++i)
    #pragma unroll
    for (int cf = 0; cf < 2; ++cf)
      #pragma unroll
      for (int j = 0; j < 4; ++j) {
        long long o = (long long)(rowbase + i * 16 + hi * 4 + j) * 128 + w * 32 + cf * 16 + lo;
        float v = 0.5f * (qz[o] + un[o] + accg[o] + ba[i][cf][j] * inv[i][j]);
        xv[i][cf][j] = v;
        accg[o] = v;
      }
  #pragma unroll
  for (int i = 0; i < 2; ++i)
    #pragma unroll
    for (int j = 0; j < 4; ++j) {
      float ps = xv[i][0][j] + xv[i][1][j];
      float pq = xv[i][0][j] * xv[i][0][j] + xv[i][1][j] * xv[i][1][j];
      #pragma unroll
      for (int off = 1; off <= 8; off <<= 1) { ps += __shfl_xor(ps, off); pq += __shfl_xor(pq, off); }
      if (lo == 0) {
        redS[w][i * 16 + hi * 4 + j] = ps;
        redQ[w][i * 16 + hi * 4 + j] = pq;
      }
    }
  __syncthreads();
  #pragma unroll
  for (int i = 0; i < 2; ++i)
    #pragma unroll
    for (int j = 0; j < 4; ++j) {
      int row = i * 16 + hi * 4 + j;
      float S = redS[0][row] + redS[1][row] + redS[2][row] + redS[3][row];
      float Q = redQ[0][row] + redQ[1][row] + redQ[2][row] + redQ[3][row];
      float m = S * (1.f / 128.f);
      float var = Q * (1.f / 128.f) - m * m;
      float r = rsqrtf(var + 1e-5f);
      #pragma unroll
      for (int cf = 0; cf < 2; ++cf) {
        long long o = (long long)(rowbase + row) * 128 + w * 32 + cf * 16 + lo;
        xln[o] = f2us((xv[i][cf][j] - m) * r * gv[cf] + bv[cf]);
      }
    }
}

extern "C" void kernel_launch(void* const* d_in, const int* in_sizes, int n_in,
                              void* d_out, int out_size, void* d_ws, size_t ws_size,
                              hipStream_t stream) {
  const float* qz    = (const float*)d_in[0];
  const float* unary = (const float*)d_in[1];
  const float* tuw   = (const float*)d_in[2];
  const float* tvw   = (const float*)d_in[3];
  const float* cuw   = (const float*)d_in[4];
  const float* cvw   = (const float*)d_in[5];
  const float* topic = (const float*)d_in[6];
  const float* gam   = (const float*)d_in[7];
  const float* bet   = (const float*)d_in[8];
  const float* w1    = (const float*)d_in[9];
  const float* b1    = (const float*)d_in[10];
  const float* w2    = (const float*)d_in[11];
  const float* b2    = (const float*)d_in[12];
  float* out = (float*)d_out;

  char* base = (char*)d_ws;
  u16*   qzn16  = (u16*)base;                    // NEL bf16
  float* accb   = (float*)(base + NEL * 2);      // NEL f32 (m_t+m_c+m_g, then x)
  u16*   bufU16 = (u16*)(base + NEL * 6);        // NEL bf16 (tu / cuT / xln)
  u16*   bufV16 = (u16*)(base + NEL * 8);        // NEL bf16 (tv / cvT / hmid)
  u16*   wbf    = (u16*)(base + NEL * 10);       // 294912 bf16 weights
  u16*   topicB = wbf + 294912;                  // 262144
  u16*   topicT = topicB + 262144;               // 262144

  convert_weights<<<576, 256, 0, stream>>>(tuw, tvw, cuw, cvw, w1, w2, wbf);
  topic_transpose<<<32, 256, 0, stream>>>(topic, topicB, topicT);
  // 1. qzn = LN(qz) (bf16)
  ln_kernel<<<16384, 256, 0, stream>>>(qz, gam, bet, qzn16);
  // 2. tu, tv (bf16, dual)
  gemm_dual<4><<<1024, 256, 0, stream>>>(qzn16, wbf, wbf + 65536, bufU16, bufV16);
  // 3. time attention -> accb (=)
  time_attn<<<512, 256, 0, stream>>>(bufU16, bufV16, qzn16, accb);
  // 4. cu, cv (bf16, transposed layout [b,p,c,o], dual)
  gemm_dual<5><<<1024, 256, 0, stream>>>(qzn16, wbf + 131072, wbf + 196608, bufU16, bufV16);
  // 5. channel attention -> accb (+=)
  chan_attn<<<512, 256, 0, stream>>>(bufU16, bufV16, qzn16, accb);
  // 6. topic + combine + LN2 -> accb = x, bufU16 = xln
  topic_fuse<<<2048, 256, 0, stream>>>(qzn16, topicB, topicT, qz, unary, gam, bet, accb, bufU16);
  // 7. hmid = gelu(xln @ w1^T + b1) (bf16)
  gemm128<2><<<1024, 256, 0, stream>>>(bufU16, wbf + 262144, b1, nullptr, nullptr, bufV16);
  // 8. out = x + hmid @ w2^T + b2  (f32)
  gemm128<3><<<1024, 256, 0, stream>>>(bufV16, wbf + 278528, b2, accb, out, nullptr);
}